// Round 22
// baseline (148.148 us; speedup 1.0000x reference)
//
#include <hip/hip_runtime.h>
#include <math.h>

#define B_ 4
#define T_ 1024
#define D_ 1024
#define H_ 16
#define DH_ 64
#define NCAT 2112   // 1024 (Q) + 1024 (K) + 64 (V)

typedef unsigned short u16;
typedef unsigned int u32;
typedef __attribute__((ext_vector_type(8))) short bf16x8;
typedef __attribute__((ext_vector_type(4))) float f32x4;

// log2-domain score scale: DH^-0.5 * log2(e)  (pre-folded into Q at GEMM)
#define SCALE2 0.18033688f
#define LSTR 72   // LDS row stride in u16: 144 B = 9*16 B (aligned, 2-way banks)

__device__ __forceinline__ u16 bf16rne(float f) {
  u32 u = __float_as_uint(f);
  u32 r = (u + 0x7fffu + ((u >> 16) & 1u)) >> 16;
  return (u16)r;
}
__device__ __forceinline__ float bf16tof(u16 h) {
  return __uint_as_float((u32)h << 16);
}
// pack 2 f32 -> 2 bf16 in one instr (T12 recipe; P-pack only)
__device__ __forceinline__ u32 cvtpk(float lo, float hi) {
  u32 r;
  asm("v_cvt_pk_bf16_f32 %0, %1, %2" : "=v"(r) : "v"(lo), "v"(hi));
  return r;
}

// async global->LDS, 16B per lane; LDS dest = wave-uniform base + lane*16
__device__ __forceinline__ void gload_lds16(const u16* g, u16* l) {
  __builtin_amdgcn_global_load_lds(
      (const __attribute__((address_space(1))) unsigned int*)g,
      (__attribute__((address_space(3))) unsigned int*)l, 16, 0, 0);
}

// ---------------------------------------------------------------------------
// prep: x bf16-round (blocks 0..2047) + weight transposes/round + bias concat
// (blocks 2048..2832) in ONE launch.
// ---------------------------------------------------------------------------
__global__ __launch_bounds__(256) void prep(
    const float* __restrict__ x,
    const float* __restrict__ Wq, const float* __restrict__ Wk,
    const float* __restrict__ Wv, const float* __restrict__ Wo,
    const float* __restrict__ bq, const float* __restrict__ bk,
    const float* __restrict__ bv,
    u16* __restrict__ xhi,
    u16* __restrict__ WcThi, u16* __restrict__ WoThi,
    float* __restrict__ bcat) {
  __shared__ float Ws[64][65];
  const int t = threadIdx.x;
  if (blockIdx.x < 2048) {  // rowconv part
    size_t i = ((size_t)blockIdx.x * 256 + t) * 8;
    float4 v0 = *(const float4*)&x[i];
    float4 v1 = *(const float4*)&x[i + 4];
    float vv[8] = {v0.x, v0.y, v0.z, v0.w, v1.x, v1.y, v1.z, v1.w};
    u32 uh[4];
#pragma unroll
    for (int j = 0; j < 4; j++)
      uh[j] = (u32)bf16rne(vv[2 * j]) | ((u32)bf16rne(vv[2 * j + 1]) << 16);
    *(uint4*)&xhi[i] = make_uint4(uh[0], uh[1], uh[2], uh[3]);
    return;
  }
  const int blk = blockIdx.x - 2048;
  if (blk == 784) {
    for (int i = t; i < NCAT; i += 256)
      bcat[i] = (i < 1024) ? bq[i] : ((i < 2048) ? bk[i - 1024] : bv[i - 2048]);
    return;
  }
  const float* W;
  u16* Thi;
  int roff, Nw, bx, by;
  if (blk < 256)      { W = Wq; Thi = WcThi; roff = 0;    Nw = 1024; bx = blk & 15;         by = blk >> 4; }
  else if (blk < 512) { W = Wk; Thi = WcThi; roff = 1024; Nw = 1024; bx = (blk - 256) & 15; by = (blk - 256) >> 4; }
  else if (blk < 768) { W = Wo; Thi = WoThi; roff = 0;    Nw = 1024; bx = (blk - 512) & 15; by = (blk - 512) >> 4; }
  else                { W = Wv; Thi = WcThi; roff = 2048; Nw = 64;   bx = 0;                by = blk - 768; }

  const int n0 = bx * 64, k0 = by * 64;
#pragma unroll
  for (int rr = 0; rr < 4; rr++) {
    int r = rr * 16 + (t >> 4);
    int c = (t & 15) * 4;
    float4 v = *(const float4*)&W[(size_t)(k0 + r) * Nw + n0 + c];
    Ws[r][c] = v.x; Ws[r][c + 1] = v.y; Ws[r][c + 2] = v.z; Ws[r][c + 3] = v.w;
  }
  __syncthreads();
  const int n = t >> 2, kc = t & 3;
  u32 uh[8];
#pragma unroll
  for (int j2 = 0; j2 < 8; j2++) {
    u16 h0 = bf16rne(Ws[kc * 16 + j2 * 2 + 0][n]);
    u16 h1 = bf16rne(Ws[kc * 16 + j2 * 2 + 1][n]);
    uh[j2] = (u32)h0 | ((u32)h1 << 16);
  }
  size_t base = (size_t)(roff + n0 + n) * 1024 + k0 + kc * 16;
  *(uint4*)&Thi[base]     = make_uint4(uh[0], uh[1], uh[2], uh[3]);
  *(uint4*)&Thi[base + 8] = make_uint4(uh[4], uh[5], uh[6], uh[7]);
}

// ---------------------------------------------------------------------------
// QKV bf16 MFMA GEMM, 1-pass, BK=64 (r13-proven indexing), m97 staging
// (global_load_lds 16B, linear LDS), 128 x 128 tile, 4 waves (2x2),
// 2-barrier loop, bijective XCD swizzle. mfma(B,A) -> D[n][m].
// Q pre-scaled by SCALE2 -> QK; K -> QK; V -> Vt transposed.
// ---------------------------------------------------------------------------
__global__ __launch_bounds__(256) void mfma_gemm_qkv(
    const u16* __restrict__ Ahi, const u16* __restrict__ Bhi,
    const float* __restrict__ bias,
    u16* __restrict__ QK, u16* __restrict__ Vt) {
  __shared__ u16 Ah[128][64];
  __shared__ u16 Bh[128][64];
  const int tid = threadIdx.x;
  const int lane = tid & 63, wid = tid >> 6;
  const int wr = wid >> 1, wc = wid & 1;
  const int nb8 = 544 >> 3;
  const int swz = (blockIdx.x & 7) * nb8 + (blockIdx.x >> 3);
  const int m0 = (swz % 32) * 128, n0 = (swz / 32) * 128;
  const int Kd = 1024, Nvalid = NCAT;
  f32x4 acc[4][4];
#pragma unroll
  for (int i = 0; i < 4; i++)
#pragma unroll
    for (int j = 0; j < 4; j++) {
      acc[i][j][0] = 0.f; acc[i][j][1] = 0.f;
      acc[i][j][2] = 0.f; acc[i][j][3] = 0.f;
    }
  const int fo = 8 * (lane >> 4);
  const int fr = lane & 15;
  const int srow = lane >> 3;        // row within an 8-row chunk
  const int scol = (lane & 7) * 8;   // u16 col within BK=64

#pragma unroll 1
  for (int k0 = 0; k0 < Kd; k0 += 64) {
#pragma unroll
    for (int c = 0; c < 4; c++) {
      int chunk = wid * 4 + c;       // 16 chunks of 8 rows
      size_t ga = (size_t)(m0 + chunk * 8 + srow) * Kd + k0 + scol;
      gload_lds16(&Ahi[ga], ((u16*)Ah) + chunk * 512);
      int grow = n0 + chunk * 8 + srow;
      if (grow >= Nvalid) grow = Nvalid - 1;
      size_t gb = (size_t)grow * Kd + k0 + scol;
      gload_lds16(&Bhi[gb], ((u16*)Bh) + chunk * 512);
    }
    __syncthreads();
#pragma unroll
    for (int ks = 0; ks < 2; ks++) {
      bf16x8 bhf[4];
#pragma unroll
      for (int nf = 0; nf < 4; nf++) {
        int r = wc * 64 + nf * 16 + fr;
        bhf[nf] = *(bf16x8*)&Bh[r][ks * 32 + fo];
      }
#pragma unroll
      for (int mf = 0; mf < 4; mf++) {
        int r = wr * 64 + mf * 16 + fr;
        bf16x8 ahf = *(bf16x8*)&Ah[r][ks * 32 + fo];
#pragma unroll
        for (int nf = 0; nf < 4; nf++)
          acc[mf][nf] = __builtin_amdgcn_mfma_f32_16x16x32_bf16(bhf[nf], ahf, acc[mf][nf], 0, 0, 0);
      }
    }
    __syncthreads();
  }
  const int rq = lane >> 4;
#pragma unroll
  for (int mf = 0; mf < 4; mf++) {
    int m = m0 + wr * 64 + mf * 16 + fr;
#pragma unroll
    for (int nf = 0; nf < 4; nf++) {
      int nb = n0 + wc * 64 + nf * 16 + rq * 4;
      if (nb < Nvalid) {
        float4 b4 = *(const float4*)&bias[nb];
        float v0 = acc[mf][nf][0] + b4.x;
        float v1 = acc[mf][nf][1] + b4.y;
        float v2 = acc[mf][nf][2] + b4.z;
        float v3 = acc[mf][nf][3] + b4.w;
        if (nb < 1024) {               // Q: pre-scaled by SCALE2
          v0 *= SCALE2; v1 *= SCALE2; v2 *= SCALE2; v3 *= SCALE2;
          *(uint2*)&QK[(size_t)m * 2048 + nb] =
              make_uint2((u32)bf16rne(v0) | ((u32)bf16rne(v1) << 16),
                         (u32)bf16rne(v2) | ((u32)bf16rne(v3) << 16));
        } else if (nb < 2048) {        // K: plain bf16
          *(uint2*)&QK[(size_t)m * 2048 + nb] =
              make_uint2((u32)bf16rne(v0) | ((u32)bf16rne(v1) << 16),
                         (u32)bf16rne(v2) | ((u32)bf16rne(v3) << 16));
        } else {                       // V: transposed; contiguous in m
          Vt[(size_t)(nb - 2048 + 0) * 4096 + m] = bf16rne(v0);
          Vt[(size_t)(nb - 2048 + 1) * 4096 + m] = bf16rne(v1);
          Vt[(size_t)(nb - 2048 + 2) * 4096 + m] = bf16rne(v2);
          Vt[(size_t)(nb - 2048 + 3) * 4096 + m] = bf16rne(v3);
        }
      }
    }
  }
}

// ---------------------------------------------------------------------------
// MFMA flash attention, 8 WAVES (512 thr), 128 q rows/block.
// grid = B*H*(T/128) = 512 (XCD-swizzled). Single-buffer K/V LDS +
// async-split. Q pre-scaled -> S log2-domain. Defer-max THR=8.
// setprio around MFMA. PV swapped: mfma(V, P) -> O[d][q=l15].
// ---------------------------------------------------------------------------
__global__ __launch_bounds__(512) void attn_fused_mfma(
    const u16* __restrict__ QK, const u16* __restrict__ Vt,
    float* __restrict__ mrow, float* __restrict__ linv,
    u16* __restrict__ ophi) {
  __shared__ u16 Kh_s[64][LSTR];
  __shared__ u16 Vt_s[64][LSTR];
  __shared__ u16 P_s[8][16][LSTR];
  const int bi0 = blockIdx.x;
  const int bi = (bi0 & 7) * 64 + (bi0 >> 3);   // XCD swizzle (512 = 8*64)
  const int qt = bi & 7, h = (bi >> 3) & 15, b = bi >> 7;
  const int tid = threadIdx.x;
  const int lane = tid & 63, w = tid >> 6;      // 8 waves
  const int l15 = lane & 15, g = lane >> 4;
  const int q0 = qt * 128 + w * 16;
  const int sr = tid >> 3, scs = (tid & 7) * 8; // staging: 1 uint4/thread/array
  bf16x8 qh[2];
  {
    size_t qoff = (size_t)(b * T_ + q0 + l15) * 2048 + h * DH_;
    qh[0] = *(const bf16x8*)&QK[qoff + 8 * g];
    qh[1] = *(const bf16x8*)&QK[qoff + 32 + 8 * g];
  }
  float m_run = -1e30f, l_run = 0.f;
  f32x4 acc_o[4];
#pragma unroll
  for (int nf = 0; nf < 4; nf++) {
    acc_o[nf][0] = 0.f; acc_o[nf][1] = 0.f; acc_o[nf][2] = 0.f; acc_o[nf][3] = 0.f;
  }

  uint4 kreg, vreg;
#define LOAD_TILE(kt_)                                                        \
  {                                                                           \
    kreg = *(const uint4*)&QK[(size_t)(b * T_ + (kt_) * 64 + sr) * 2048 + 1024 + h * DH_ + scs]; \
    vreg = *(const uint4*)&Vt[(size_t)sr * 4096 + b * T_ + (kt_) * 64 + scs]; \
  }
#define STORE_TILE()                                                          \
  {                                                                           \
    *(uint4*)&Kh_s[sr][scs] = kreg;                                           \
    *(uint4*)&Vt_s[sr][scs] = vreg;                                           \
  }

  LOAD_TILE(0);

#pragma unroll 1
  for (int kt = 0; kt < 16; kt++) {
    STORE_TILE();
    __syncthreads();
    if (kt < 15) LOAD_TILE(kt + 1);
    f32x4 accs[4];
#pragma unroll
    for (int mf = 0; mf < 4; mf++) {
      accs[mf][0] = 0.f; accs[mf][1] = 0.f; accs[mf][2] = 0.f; accs[mf][3] = 0.f;
    }
    __builtin_amdgcn_s_setprio(1);
#pragma unroll
    for (int mf = 0; mf < 4; mf++) {
#pragma unroll
      for (int ks = 0; ks < 2; ks++) {
        bf16x8 kh = *(bf16x8*)&Kh_s[mf * 16 + l15][ks * 32 + 8 * g];
        accs[mf] = __builtin_amdgcn_mfma_f32_16x16x32_bf16(kh, qh[ks], accs[mf], 0, 0, 0);
      }
    }
    __builtin_amdgcn_s_setprio(0);
    float t0 = fmaxf(fmaxf(accs[0][0], accs[0][1]), fmaxf(accs[0][2], accs[0][3]));
    float t1 = fmaxf(fmaxf(accs[1][0], accs[1][1]), fmaxf(accs[1][2], accs[1][3]));
    float t2 = fmaxf(fmaxf(accs[2][0], accs[2][1]), fmaxf(accs[2][2], accs[2][3]));
    float t3 = fmaxf(fmaxf(accs[3][0], accs[3][1]), fmaxf(accs[3][2], accs[3][3]));
    float tm = fmaxf(fmaxf(t0, t1), fmaxf(t2, t3));
    tm = fmaxf(tm, __shfl_xor(tm, 16));
    tm = fmaxf(tm, __shfl_xor(tm, 32));
    if (!__all(tm <= m_run + 8.f)) {
      float m_new = fmaxf(m_run, tm);
      float crs = __builtin_amdgcn_exp2f(m_run - m_new);
      l_run *= crs;
#pragma unroll
      for (int nf = 0; nf < 4; nf++)
#pragma unroll
        for (int r = 0; r < 4; r++) acc_o[nf][r] *= crs;
      m_run = m_new;
    }
    float ts = 0.f;
#pragma unroll
    for (int mf = 0; mf < 4; mf++) {
      float p0 = __builtin_amdgcn_exp2f(accs[mf][0] - m_run);
      float p1 = __builtin_amdgcn_exp2f(accs[mf][1] - m_run);
      float p2 = __builtin_amdgcn_exp2f(accs[mf][2] - m_run);
      float p3 = __builtin_amdgcn_exp2f(accs[mf][3] - m_run);
      ts += (p0 + p1) + (p2 + p3);
      *(uint2*)&P_s[w][l15][16 * mf + 4 * g] =
          make_uint2(cvtpk(p0, p1), cvtpk(p2, p3));
    }
    ts += __shfl_xor(ts, 16);
    ts += __shfl_xor(ts, 32);
    l_run += ts;
    bf16x8 pa[2];
    pa[0] = *(bf16x8*)&P_s[w][l15][8 * g];
    pa[1] = *(bf16x8*)&P_s[w][l15][32 + 8 * g];
    __builtin_amdgcn_s_setprio(1);
#pragma unroll
    for (int nf = 0; nf < 4; nf++) {
#pragma unroll
      for (int ks = 0; ks < 2; ks++) {
        bf16x8 vb = *(bf16x8*)&Vt_s[nf * 16 + l15][ks * 32 + 8 * g];
        acc_o[nf] = __builtin_amdgcn_mfma_f32_16x16x32_bf16(vb, pa[ks], acc_o[nf], 0, 0, 0);
      }
    }
    __builtin_amdgcn_s_setprio(0);
    __syncthreads();
  }
#undef LOAD_TILE
#undef STORE_TILE
  float li = 1.0f / l_run;
  if (g == 0) {
    int idx = (b * H_ + h) * T_ + q0 + l15;
    mrow[idx] = m_run;
    linv[idx] = li;
  }
  size_t obase = (size_t)(b * T_ + q0 + l15) * D_ + h * DH_;
#pragma unroll
  for (int nf = 0; nf < 4; nf++) {
    float v0 = acc_o[nf][0] * li, v1 = acc_o[nf][1] * li;
    float v2 = acc_o[nf][2] * li, v3 = acc_o[nf][3] * li;
    *(uint2*)&ophi[obase + nf * 16 + 4 * g] =
        make_uint2((u32)bf16rne(v0) | ((u32)bf16rne(v1) << 16),
                   (u32)bf16rne(v2) | ((u32)bf16rne(v3) << 16));
  }
}

// ---------------------------------------------------------------------------
// tail: Wo GEMM BK=64 (blocks 0..511) + attn_mean 4-wave (blocks 512..1535)
// in ONE launch. 256 threads; 24 KB shared pool aliased by branch.
// ---------------------------------------------------------------------------
__global__ __launch_bounds__(256) void tail(
    const u16* __restrict__ xhi, const u16* __restrict__ WoThi,
    const float* __restrict__ bo, float* __restrict__ out,
    const u16* __restrict__ QK, const float* __restrict__ mrow,
    const float* __restrict__ linv, float* __restrict__ am_out) {
  __shared__ u16 pool[64 * 64 + 128 * 64];  // 24 KB
  const int tid = threadIdx.x;
  const int lane = tid & 63, w4 = tid >> 6;
  const int l15 = lane & 15, g = lane >> 4;

  if (blockIdx.x < 512) {
    // ---- Wo GEMM: TM=64, 128-wide N tile, BK=64, 2-barrier, XCD swizzle ----
    u16(*Ah)[64] = (u16(*)[64])pool;             // [64][64]
    u16(*Bh)[64] = (u16(*)[64])(pool + 64 * 64); // [128][64]
    const int wr = w4 >> 1, wc = w4 & 1;
    const int swz = ((int)blockIdx.x & 7) * 64 + ((int)blockIdx.x >> 3);
    const int m0 = (swz % 64) * 64, n0 = (swz / 64) * 128;
    const int Kd = 1024;
    f32x4 acc[2][4];
#pragma unroll
    for (int i = 0; i < 2; i++)
#pragma unroll
      for (int j = 0; j < 4; j++) {
        acc[i][j][0] = 0.f; acc[i][j][1] = 0.f;
        acc[i][j][2] = 0.f; acc[i][j][3] = 0.f;
      }
    const int fo = 8 * g;
    const int fr = l15;
    const int srow = lane >> 3;        // row within 8-row chunk
    const int scol = (lane & 7) * 8;   // u16 col within BK=64
#pragma unroll 1
    for (int k0 = 0; k0 < Kd; k0 += 64) {
#pragma unroll
      for (int c = 0; c < 2; c++) {    // A: 64 rows = 8 chunks, 2/wave
        int chunk = w4 * 2 + c;
        size_t ga = (size_t)(m0 + chunk * 8 + srow) * Kd + k0 + scol;
        gload_lds16(&xhi[ga], ((u16*)Ah) + chunk * 512);
      }
#pragma unroll
      for (int c = 0; c < 4; c++) {    // B: 128 rows = 16 chunks, 4/wave
        int chunk = w4 * 4 + c;
        size_t gb = (size_t)(n0 + chunk * 8 + srow) * Kd + k0 + scol;
        gload_lds16(&WoThi[gb], ((u16*)Bh) + chunk * 512);
      }
      __syncthreads();
#pragma unroll
      for (int ks = 0; ks < 2; ks++) {
        bf16x8 bhf[4];
#pragma unroll
        for (int nf = 0; nf < 4; nf++) {
          int r = wc * 64 + nf * 16 + fr;
          bhf[nf] = *(bf16x8*)&Bh[r][ks * 32 + fo];
        }
#pragma unroll
        for (int mf = 0; mf < 2; mf++) {
          int r = wr * 32 + mf * 16 + fr;
          bf16x8 ahf = *(bf16x8*)&Ah[r][ks * 32 + fo];
#pragma unroll
          for (int nf = 0; nf < 4; nf++)
            acc[mf][nf] = __builtin_amdgcn_mfma_f32_16x16x32_bf16(bhf[nf], ahf, acc[mf][nf], 0, 0, 0);
        }
      }
      __syncthreads();
    }
    const int rq = g;
#pragma unroll
    for (int mf = 0; mf < 2; mf++) {
      int m = m0 + wr * 32 + mf * 16 + fr;
#pragma unroll
      for (int nf = 0; nf < 4; nf++) {
        int nb = n0 + wc * 64 + nf * 16 + rq * 4;
        float4 b4 = *(const float4*)&bo[nb];
        float4 o;
        o.x = acc[mf][nf][0] + b4.x;
        o.y = acc[mf][nf][1] + b4.y;
        o.z = acc[mf][nf][2] + b4.z;
        o.w = acc[mf][nf][3] + b4.w;
        *(float4*)&out[(size_t)m * 1024 + nb] = o;
      }
    }
  } else {
    // ---- attn_mean: 4-wave, 64 q rows x 64 k cols, 16-head loop ----
    u16(*Kh_s)[LSTR] = (u16(*)[LSTR])pool;  // [64][72] = 9.2 KB < 24 KB
    const int bi0 = (int)blockIdx.x - 512;
    const int bi = (bi0 & 7) * 128 + (bi0 >> 3);  // XCD swizzle (1024 = 8*128)
    const int kc = bi & 15, qt = (bi >> 4) & 15, b = bi >> 8;
    const int q0 = qt * 64 + w4 * 16, k0 = kc * 64;
    const int sr = tid >> 2, scs = (tid & 3) * 16;
    float am[4][4] = {};
    uint4 kreg0, kreg1;
    bf16x8 qhc0, qhc1, qhn0, qhn1;
#define LOAD_K(h_)                                                            \
    {                                                                         \
      size_t krow = (size_t)(b * T_ + k0 + sr) * 2048 + 1024 + (h_) * DH_ + scs; \
      kreg0 = *(const uint4*)&QK[krow];                                       \
      kreg1 = *(const uint4*)&QK[krow + 8];                                   \
    }
#define LOAD_Q(h_, d0, d1)                                                    \
    {                                                                         \
      size_t qoff = (size_t)(b * T_ + q0 + l15) * 2048 + (h_) * DH_;          \
      d0 = *(const bf16x8*)&QK[qoff + 8 * g];                                 \
      d1 = *(const bf16x8*)&QK[qoff + 32 + 8 * g];                            \
    }
    LOAD_K(0);
    LOAD_Q(0, qhc0, qhc1);
#pragma unroll 1
    for (int h = 0; h < H_; h++) {
      *(uint4*)&Kh_s[sr][scs]     = kreg0;
      *(uint4*)&Kh_s[sr][scs + 8] = kreg1;
      __syncthreads();
      if (h < 15) { LOAD_K(h + 1); LOAD_Q(h + 1, qhn0, qhn1); }
      f32x4 accs[4];
#pragma unroll
      for (int mf = 0; mf < 4; mf++) {
        accs[mf][0] = 0.f; accs[mf][1] = 0.f; accs[mf][2] = 0.f; accs[mf][3] = 0.f;
      }
#pragma unroll
      for (int mf = 0; mf < 4; mf++) {
        bf16x8 kh0 = *(bf16x8*)&Kh_s[mf * 16 + l15][8 * g];
        bf16x8 kh1 = *(bf16x8*)&Kh_s[mf * 16 + l15][32 + 8 * g];
        accs[mf] = __builtin_amdgcn_mfma_f32_16x16x32_bf16(kh0, qhc0, accs[mf], 0, 0, 0);
        accs[mf] = __builtin_amdgcn_mfma_f32_16x16x32_bf16(kh1, qhc1, accs[mf], 0, 0, 0);
      }
      const float mq = mrow[(b * H_ + h) * T_ + q0 + l15];
      const float li = linv[(b * H_ + h) * T_ + q0 + l15];
#pragma unroll
      for (int mf = 0; mf < 4; mf++)
#pragma unroll
        for (int r = 0; r < 4; r++)
          am[mf][r] += __builtin_amdgcn_exp2f(accs[mf][r] - mq) * li;
      __syncthreads();
      qhc0 = qhn0; qhc1 = qhn1;
    }
#undef LOAD_K
#undef LOAD_Q
    const float inv16 = 1.0f / 16.0f;
#pragma unroll
    for (int mf = 0; mf < 4; mf++) {
      float4 o;
      o.x = am[mf][0] * inv16; o.y = am[mf][1] * inv16;
      o.z = am[mf][2] * inv16; o.w = am[mf][3] * inv16;
      *(float4*)&am_out[(size_t)(b * T_ + q0 + l15) * T_ + k0 + 16 * mf + 4 * g] = o;
    }
  }
}

// ---------------------------------------------------------------------------
extern "C" void kernel_launch(void* const* d_in, const int* in_sizes, int n_in,
                              void* d_out, int out_size, void* d_ws, size_t ws_size,
                              hipStream_t stream) {
  const float* x  = (const float*)d_in[0];
  const float* Wq = (const float*)d_in[1];
  const float* bq = (const float*)d_in[2];
  const float* Wk = (const float*)d_in[3];
  const float* bk = (const float*)d_in[4];
  const float* Wv = (const float*)d_in[5];
  const float* bv = (const float*)d_in[6];
  const float* Wo = (const float*)d_in[7];
  const float* bo = (const float*)d_in[8];

  float* out = (float*)d_out;                      // [B,T,D]
  float* am  = out + (size_t)B_ * T_ * D_;         // [B,T,T]

  char* w = (char*)d_ws;
  u16* QK    = (u16*)w; w += (size_t)4096 * 2048 * 2;  // Q (pre-scaled) | K
  u16* Vt    = (u16*)w; w += (size_t)64 * 4096 * 2;
  u16* xhi   = (u16*)w; w += (size_t)4096 * 1024 * 2;  // x-hi, then out_pre hi
  u16* WcThi = (u16*)w; w += (size_t)NCAT * 1024 * 2;
  u16* WoThi = (u16*)w; w += (size_t)1024 * 1024 * 2;
  float* mrow  = (float*)w; w += (size_t)B_ * H_ * T_ * 4;
  float* linvp = (float*)w; w += (size_t)B_ * H_ * T_ * 4;
  float* bcat  = (float*)w; w += (size_t)NCAT * 4;

  prep<<<2833, 256, 0, stream>>>(x, Wq, Wk, Wv, Wo, bq, bk, bv,
                                 xhi, WcThi, WoThi, bcat);

  // QKV GEMM (1-pass, BK=64, 2-barrier, XCD-swizzled) -> QK, Vt
  mfma_gemm_qkv<<<544, 256, 0, stream>>>(xhi, WcThi, bcat, QK, Vt);

  attn_fused_mfma<<<512, 512, 0, stream>>>(QK, Vt, mrow, linvp, xhi);

  // tail: Wo GEMM (BK=64) + attn_mean fused in one launch
  tail<<<1536, 256, 0, stream>>>(xhi, WoThi, bo, out, QK, mrow, linvp, am);
}

// Round 23
// 132.431 us; speedup vs baseline: 1.1187x; 1.1187x over previous
//
#include <hip/hip_runtime.h>
#include <math.h>

#define B_ 4
#define T_ 1024
#define D_ 1024
#define H_ 16
#define DH_ 64
#define NCAT 2112   // 1024 (Q) + 1024 (K) + 64 (V)

typedef unsigned short u16;
typedef unsigned int u32;
typedef __attribute__((ext_vector_type(8))) short bf16x8;
typedef __attribute__((ext_vector_type(4))) float f32x4;

// log2-domain score scale: DH^-0.5 * log2(e)  (pre-folded into Q at GEMM)
#define SCALE2 0.18033688f
#define LSTR 72   // LDS row stride in u16: 144 B = 9*16 B (aligned, 2-way banks)

__device__ __forceinline__ u16 bf16rne(float f) {
  u32 u = __float_as_uint(f);
  u32 r = (u + 0x7fffu + ((u >> 16) & 1u)) >> 16;
  return (u16)r;
}
__device__ __forceinline__ float bf16tof(u16 h) {
  return __uint_as_float((u32)h << 16);
}
// pack 2 f32 -> 2 bf16 in one instr (T12 recipe; P-pack only)
__device__ __forceinline__ u32 cvtpk(float lo, float hi) {
  u32 r;
  asm("v_cvt_pk_bf16_f32 %0, %1, %2" : "=v"(r) : "v"(lo), "v"(hi));
  return r;
}

// async global->LDS, 16B per lane; LDS dest = wave-uniform base + lane*16
__device__ __forceinline__ void gload_lds16(const u16* g, u16* l) {
  __builtin_amdgcn_global_load_lds(
      (const __attribute__((address_space(1))) unsigned int*)g,
      (__attribute__((address_space(3))) unsigned int*)l, 16, 0, 0);
}

// ---------------------------------------------------------------------------
// prep: x bf16-round (blocks 0..2047) + weight transposes/round + bias concat
// (blocks 2048..2832) in ONE launch.
// ---------------------------------------------------------------------------
__global__ __launch_bounds__(256) void prep(
    const float* __restrict__ x,
    const float* __restrict__ Wq, const float* __restrict__ Wk,
    const float* __restrict__ Wv, const float* __restrict__ Wo,
    const float* __restrict__ bq, const float* __restrict__ bk,
    const float* __restrict__ bv,
    u16* __restrict__ xhi,
    u16* __restrict__ WcThi, u16* __restrict__ WoThi,
    float* __restrict__ bcat) {
  __shared__ float Ws[64][65];
  const int t = threadIdx.x;
  if (blockIdx.x < 2048) {  // rowconv part
    size_t i = ((size_t)blockIdx.x * 256 + t) * 8;
    float4 v0 = *(const float4*)&x[i];
    float4 v1 = *(const float4*)&x[i + 4];
    float vv[8] = {v0.x, v0.y, v0.z, v0.w, v1.x, v1.y, v1.z, v1.w};
    u32 uh[4];
#pragma unroll
    for (int j = 0; j < 4; j++)
      uh[j] = (u32)bf16rne(vv[2 * j]) | ((u32)bf16rne(vv[2 * j + 1]) << 16);
    *(uint4*)&xhi[i] = make_uint4(uh[0], uh[1], uh[2], uh[3]);
    return;
  }
  const int blk = blockIdx.x - 2048;
  if (blk == 784) {
    for (int i = t; i < NCAT; i += 256)
      bcat[i] = (i < 1024) ? bq[i] : ((i < 2048) ? bk[i - 1024] : bv[i - 2048]);
    return;
  }
  const float* W;
  u16* Thi;
  int roff, Nw, bx, by;
  if (blk < 256)      { W = Wq; Thi = WcThi; roff = 0;    Nw = 1024; bx = blk & 15;         by = blk >> 4; }
  else if (blk < 512) { W = Wk; Thi = WcThi; roff = 1024; Nw = 1024; bx = (blk - 256) & 15; by = (blk - 256) >> 4; }
  else if (blk < 768) { W = Wo; Thi = WoThi; roff = 0;    Nw = 1024; bx = (blk - 512) & 15; by = (blk - 512) >> 4; }
  else                { W = Wv; Thi = WcThi; roff = 2048; Nw = 64;   bx = 0;                by = blk - 768; }

  const int n0 = bx * 64, k0 = by * 64;
#pragma unroll
  for (int rr = 0; rr < 4; rr++) {
    int r = rr * 16 + (t >> 4);
    int c = (t & 15) * 4;
    float4 v = *(const float4*)&W[(size_t)(k0 + r) * Nw + n0 + c];
    Ws[r][c] = v.x; Ws[r][c + 1] = v.y; Ws[r][c + 2] = v.z; Ws[r][c + 3] = v.w;
  }
  __syncthreads();
  const int n = t >> 2, kc = t & 3;
  u32 uh[8];
#pragma unroll
  for (int j2 = 0; j2 < 8; j2++) {
    u16 h0 = bf16rne(Ws[kc * 16 + j2 * 2 + 0][n]);
    u16 h1 = bf16rne(Ws[kc * 16 + j2 * 2 + 1][n]);
    uh[j2] = (u32)h0 | ((u32)h1 << 16);
  }
  size_t base = (size_t)(roff + n0 + n) * 1024 + k0 + kc * 16;
  *(uint4*)&Thi[base]     = make_uint4(uh[0], uh[1], uh[2], uh[3]);
  *(uint4*)&Thi[base + 8] = make_uint4(uh[4], uh[5], uh[6], uh[7]);
}

// ---------------------------------------------------------------------------
// QKV bf16 MFMA GEMM, 1-pass, BK=32, m97 staging (global_load_lds 16B,
// linear LDS), 128 x 128 tile, 4 waves (2x2), 2-barrier loop (race-proven),
// bijective XCD swizzle. mfma(B,A) -> D[n][m].
// Q pre-scaled by SCALE2 -> QK; K -> QK; V -> Vt transposed.
// ---------------------------------------------------------------------------
__global__ __launch_bounds__(256) void mfma_gemm_qkv(
    const u16* __restrict__ Ahi, const u16* __restrict__ Bhi,
    const float* __restrict__ bias,
    u16* __restrict__ QK, u16* __restrict__ Vt) {
  __shared__ u16 Ah[128][32];
  __shared__ u16 Bh[128][32];
  const int tid = threadIdx.x;
  const int lane = tid & 63, wid = tid >> 6;
  const int wr = wid >> 1, wc = wid & 1;
  const int nb8 = 544 >> 3;
  const int swz = (blockIdx.x & 7) * nb8 + (blockIdx.x >> 3);
  const int m0 = (swz % 32) * 128, n0 = (swz / 32) * 128;
  const int Kd = 1024, Nvalid = NCAT;
  f32x4 acc[4][4];
#pragma unroll
  for (int i = 0; i < 4; i++)
#pragma unroll
    for (int j = 0; j < 4; j++) {
      acc[i][j][0] = 0.f; acc[i][j][1] = 0.f;
      acc[i][j][2] = 0.f; acc[i][j][3] = 0.f;
    }
  const int fo = 8 * (lane >> 4);
  const int fr = lane & 15;
  const int srow = lane >> 2;
  const int scol = (lane & 3) * 8;

#pragma unroll 1
  for (int k0 = 0; k0 < Kd; k0 += 32) {
#pragma unroll
    for (int c = 0; c < 2; c++) {
      int chunk = wid * 2 + c;
      size_t ga = (size_t)(m0 + chunk * 16 + srow) * Kd + k0 + scol;
      gload_lds16(&Ahi[ga], ((u16*)Ah) + chunk * 512);
      int grow = n0 + chunk * 16 + srow;
      if (grow >= Nvalid) grow = Nvalid - 1;
      size_t gb = (size_t)grow * Kd + k0 + scol;
      gload_lds16(&Bhi[gb], ((u16*)Bh) + chunk * 512);
    }
    __syncthreads();
    bf16x8 bhf[4];
#pragma unroll
    for (int nf = 0; nf < 4; nf++) {
      int r = wc * 64 + nf * 16 + fr;
      bhf[nf] = *(bf16x8*)&Bh[r][fo];
    }
#pragma unroll
    for (int mf = 0; mf < 4; mf++) {
      int r = wr * 64 + mf * 16 + fr;
      bf16x8 ahf = *(bf16x8*)&Ah[r][fo];
#pragma unroll
      for (int nf = 0; nf < 4; nf++)
        acc[mf][nf] = __builtin_amdgcn_mfma_f32_16x16x32_bf16(bhf[nf], ahf, acc[mf][nf], 0, 0, 0);
    }
    __syncthreads();
  }
  const int rq = lane >> 4;
#pragma unroll
  for (int mf = 0; mf < 4; mf++) {
    int m = m0 + wr * 64 + mf * 16 + fr;
#pragma unroll
    for (int nf = 0; nf < 4; nf++) {
      int nb = n0 + wc * 64 + nf * 16 + rq * 4;
      if (nb < Nvalid) {
        float4 b4 = *(const float4*)&bias[nb];
        float v0 = acc[mf][nf][0] + b4.x;
        float v1 = acc[mf][nf][1] + b4.y;
        float v2 = acc[mf][nf][2] + b4.z;
        float v3 = acc[mf][nf][3] + b4.w;
        if (nb < 1024) {               // Q: pre-scaled by SCALE2
          v0 *= SCALE2; v1 *= SCALE2; v2 *= SCALE2; v3 *= SCALE2;
          *(uint2*)&QK[(size_t)m * 2048 + nb] =
              make_uint2((u32)bf16rne(v0) | ((u32)bf16rne(v1) << 16),
                         (u32)bf16rne(v2) | ((u32)bf16rne(v3) << 16));
        } else if (nb < 2048) {        // K: plain bf16
          *(uint2*)&QK[(size_t)m * 2048 + nb] =
              make_uint2((u32)bf16rne(v0) | ((u32)bf16rne(v1) << 16),
                         (u32)bf16rne(v2) | ((u32)bf16rne(v3) << 16));
        } else {                       // V: transposed; contiguous in m
          Vt[(size_t)(nb - 2048 + 0) * 4096 + m] = bf16rne(v0);
          Vt[(size_t)(nb - 2048 + 1) * 4096 + m] = bf16rne(v1);
          Vt[(size_t)(nb - 2048 + 2) * 4096 + m] = bf16rne(v2);
          Vt[(size_t)(nb - 2048 + 3) * 4096 + m] = bf16rne(v3);
        }
      }
    }
  }
}

// ---------------------------------------------------------------------------
// MFMA flash attention, 8 WAVES (512 thr), 128 q rows/block.
// grid = B*H*(T/128) = 512 (XCD-swizzled). Single-buffer K/V LDS +
// async-split. Q pre-scaled -> S log2-domain. Defer-max THR=8.
// setprio around MFMA. PV swapped: mfma(V, P) -> O[d][q=l15].
// ---------------------------------------------------------------------------
__global__ __launch_bounds__(512) void attn_fused_mfma(
    const u16* __restrict__ QK, const u16* __restrict__ Vt,
    float* __restrict__ mrow, float* __restrict__ linv,
    u16* __restrict__ ophi) {
  __shared__ u16 Kh_s[64][LSTR];
  __shared__ u16 Vt_s[64][LSTR];
  __shared__ u16 P_s[8][16][LSTR];
  const int bi0 = blockIdx.x;
  const int bi = (bi0 & 7) * 64 + (bi0 >> 3);   // XCD swizzle (512 = 8*64)
  const int qt = bi & 7, h = (bi >> 3) & 15, b = bi >> 7;
  const int tid = threadIdx.x;
  const int lane = tid & 63, w = tid >> 6;      // 8 waves
  const int l15 = lane & 15, g = lane >> 4;
  const int q0 = qt * 128 + w * 16;
  const int sr = tid >> 3, scs = (tid & 7) * 8; // staging: 1 uint4/thread/array
  bf16x8 qh[2];
  {
    size_t qoff = (size_t)(b * T_ + q0 + l15) * 2048 + h * DH_;
    qh[0] = *(const bf16x8*)&QK[qoff + 8 * g];
    qh[1] = *(const bf16x8*)&QK[qoff + 32 + 8 * g];
  }
  float m_run = -1e30f, l_run = 0.f;
  f32x4 acc_o[4];
#pragma unroll
  for (int nf = 0; nf < 4; nf++) {
    acc_o[nf][0] = 0.f; acc_o[nf][1] = 0.f; acc_o[nf][2] = 0.f; acc_o[nf][3] = 0.f;
  }

  uint4 kreg, vreg;
#define LOAD_TILE(kt_)                                                        \
  {                                                                           \
    kreg = *(const uint4*)&QK[(size_t)(b * T_ + (kt_) * 64 + sr) * 2048 + 1024 + h * DH_ + scs]; \
    vreg = *(const uint4*)&Vt[(size_t)sr * 4096 + b * T_ + (kt_) * 64 + scs]; \
  }
#define STORE_TILE()                                                          \
  {                                                                           \
    *(uint4*)&Kh_s[sr][scs] = kreg;                                           \
    *(uint4*)&Vt_s[sr][scs] = vreg;                                           \
  }

  LOAD_TILE(0);

#pragma unroll 1
  for (int kt = 0; kt < 16; kt++) {
    STORE_TILE();
    __syncthreads();
    if (kt < 15) LOAD_TILE(kt + 1);
    f32x4 accs[4];
#pragma unroll
    for (int mf = 0; mf < 4; mf++) {
      accs[mf][0] = 0.f; accs[mf][1] = 0.f; accs[mf][2] = 0.f; accs[mf][3] = 0.f;
    }
    __builtin_amdgcn_s_setprio(1);
#pragma unroll
    for (int mf = 0; mf < 4; mf++) {
#pragma unroll
      for (int ks = 0; ks < 2; ks++) {
        bf16x8 kh = *(bf16x8*)&Kh_s[mf * 16 + l15][ks * 32 + 8 * g];
        accs[mf] = __builtin_amdgcn_mfma_f32_16x16x32_bf16(kh, qh[ks], accs[mf], 0, 0, 0);
      }
    }
    __builtin_amdgcn_s_setprio(0);
    float t0 = fmaxf(fmaxf(accs[0][0], accs[0][1]), fmaxf(accs[0][2], accs[0][3]));
    float t1 = fmaxf(fmaxf(accs[1][0], accs[1][1]), fmaxf(accs[1][2], accs[1][3]));
    float t2 = fmaxf(fmaxf(accs[2][0], accs[2][1]), fmaxf(accs[2][2], accs[2][3]));
    float t3 = fmaxf(fmaxf(accs[3][0], accs[3][1]), fmaxf(accs[3][2], accs[3][3]));
    float tm = fmaxf(fmaxf(t0, t1), fmaxf(t2, t3));
    tm = fmaxf(tm, __shfl_xor(tm, 16));
    tm = fmaxf(tm, __shfl_xor(tm, 32));
    if (!__all(tm <= m_run + 8.f)) {
      float m_new = fmaxf(m_run, tm);
      float crs = __builtin_amdgcn_exp2f(m_run - m_new);
      l_run *= crs;
#pragma unroll
      for (int nf = 0; nf < 4; nf++)
#pragma unroll
        for (int r = 0; r < 4; r++) acc_o[nf][r] *= crs;
      m_run = m_new;
    }
    float ts = 0.f;
#pragma unroll
    for (int mf = 0; mf < 4; mf++) {
      float p0 = __builtin_amdgcn_exp2f(accs[mf][0] - m_run);
      float p1 = __builtin_amdgcn_exp2f(accs[mf][1] - m_run);
      float p2 = __builtin_amdgcn_exp2f(accs[mf][2] - m_run);
      float p3 = __builtin_amdgcn_exp2f(accs[mf][3] - m_run);
      ts += (p0 + p1) + (p2 + p3);
      *(uint2*)&P_s[w][l15][16 * mf + 4 * g] =
          make_uint2(cvtpk(p0, p1), cvtpk(p2, p3));
    }
    ts += __shfl_xor(ts, 16);
    ts += __shfl_xor(ts, 32);
    l_run += ts;
    bf16x8 pa[2];
    pa[0] = *(bf16x8*)&P_s[w][l15][8 * g];
    pa[1] = *(bf16x8*)&P_s[w][l15][32 + 8 * g];
    __builtin_amdgcn_s_setprio(1);
#pragma unroll
    for (int nf = 0; nf < 4; nf++) {
#pragma unroll
      for (int ks = 0; ks < 2; ks++) {
        bf16x8 vb = *(bf16x8*)&Vt_s[nf * 16 + l15][ks * 32 + 8 * g];
        acc_o[nf] = __builtin_amdgcn_mfma_f32_16x16x32_bf16(vb, pa[ks], acc_o[nf], 0, 0, 0);
      }
    }
    __builtin_amdgcn_s_setprio(0);
    __syncthreads();
  }
#undef LOAD_TILE
#undef STORE_TILE
  float li = 1.0f / l_run;
  if (g == 0) {
    int idx = (b * H_ + h) * T_ + q0 + l15;
    mrow[idx] = m_run;
    linv[idx] = li;
  }
  size_t obase = (size_t)(b * T_ + q0 + l15) * D_ + h * DH_;
#pragma unroll
  for (int nf = 0; nf < 4; nf++) {
    float v0 = acc_o[nf][0] * li, v1 = acc_o[nf][1] * li;
    float v2 = acc_o[nf][2] * li, v3 = acc_o[nf][3] * li;
    *(uint2*)&ophi[obase + nf * 16 + 4 * g] =
        make_uint2((u32)bf16rne(v0) | ((u32)bf16rne(v1) << 16),
                   (u32)bf16rne(v2) | ((u32)bf16rne(v3) << 16));
  }
}

// ---------------------------------------------------------------------------
// tail: Wo GEMM (blocks 0..511) + attn_mean 4-wave (blocks 512..1535) in ONE
// launch — the two are independent (both depend only on attn_fused) and
// co-schedule across CUs. 256 threads; 12 KB shared pool aliased by branch.
// ---------------------------------------------------------------------------
__global__ __launch_bounds__(256) void tail(
    const u16* __restrict__ xhi, const u16* __restrict__ WoThi,
    const float* __restrict__ bo, float* __restrict__ out,
    const u16* __restrict__ QK, const float* __restrict__ mrow,
    const float* __restrict__ linv, float* __restrict__ am_out) {
  __shared__ u16 pool[64 * 32 + 128 * 32];  // 12 KB
  const int tid = threadIdx.x;
  const int lane = tid & 63, w4 = tid >> 6;
  const int l15 = lane & 15, g = lane >> 4;

  if (blockIdx.x < 512) {
    // ---- Wo GEMM: TM=64, 128-wide N tile, BK=32, 2-barrier, XCD swizzle ----
    u16(*Ah)[32] = (u16(*)[32])pool;             // [64][32]
    u16(*Bh)[32] = (u16(*)[32])(pool + 64 * 32); // [128][32]
    const int wr = w4 >> 1, wc = w4 & 1;
    const int swz = ((int)blockIdx.x & 7) * 64 + ((int)blockIdx.x >> 3);
    const int m0 = (swz % 64) * 64, n0 = (swz / 64) * 128;
    const int Kd = 1024;
    f32x4 acc[2][4];
#pragma unroll
    for (int i = 0; i < 2; i++)
#pragma unroll
      for (int j = 0; j < 4; j++) {
        acc[i][j][0] = 0.f; acc[i][j][1] = 0.f;
        acc[i][j][2] = 0.f; acc[i][j][3] = 0.f;
      }
    const int fo = 8 * g;
    const int fr = l15;
    const int srow = lane >> 2;
    const int scol = (lane & 3) * 8;
#pragma unroll 1
    for (int k0 = 0; k0 < Kd; k0 += 32) {
      {
        int chunk = w4;  // A: 64x32 = 4 chunks, 1 per wave
        size_t ga = (size_t)(m0 + chunk * 16 + srow) * Kd + k0 + scol;
        gload_lds16(&xhi[ga], ((u16*)Ah) + chunk * 512);
      }
#pragma unroll
      for (int c = 0; c < 2; c++) {
        int chunk = w4 * 2 + c;  // B: 128x32 = 8 chunks
        size_t gb = (size_t)(n0 + chunk * 16 + srow) * Kd + k0 + scol;
        gload_lds16(&WoThi[gb], ((u16*)Bh) + chunk * 512);
      }
      __syncthreads();
      bf16x8 bhf[4];
#pragma unroll
      for (int nf = 0; nf < 4; nf++) {
        int r = wc * 64 + nf * 16 + fr;
        bhf[nf] = *(bf16x8*)&Bh[r][fo];
      }
#pragma unroll
      for (int mf = 0; mf < 2; mf++) {
        int r = wr * 32 + mf * 16 + fr;
        bf16x8 ahf = *(bf16x8*)&Ah[r][fo];
#pragma unroll
        for (int nf = 0; nf < 4; nf++)
          acc[mf][nf] = __builtin_amdgcn_mfma_f32_16x16x32_bf16(bhf[nf], ahf, acc[mf][nf], 0, 0, 0);
      }
      __syncthreads();
    }
    const int rq = g;
#pragma unroll
    for (int mf = 0; mf < 2; mf++) {
      int m = m0 + wr * 32 + mf * 16 + fr;
#pragma unroll
      for (int nf = 0; nf < 4; nf++) {
        int nb = n0 + wc * 64 + nf * 16 + rq * 4;
        float4 b4 = *(const float4*)&bo[nb];
        float4 o;
        o.x = acc[mf][nf][0] + b4.x;
        o.y = acc[mf][nf][1] + b4.y;
        o.z = acc[mf][nf][2] + b4.z;
        o.w = acc[mf][nf][3] + b4.w;
        *(float4*)&out[(size_t)m * 1024 + nb] = o;
      }
    }
  } else {
    // ---- attn_mean: 4-wave, 64 q rows x 64 k cols, 16-head loop ----
    u16(*Kh_s)[LSTR] = (u16(*)[LSTR])pool;  // [64][72] = 9.2 KB < 12 KB
    const int bi0 = (int)blockIdx.x - 512;
    const int bi = (bi0 & 7) * 128 + (bi0 >> 3);  // XCD swizzle (1024 = 8*128)
    const int kc = bi & 15, qt = (bi >> 4) & 15, b = bi >> 8;
    const int q0 = qt * 64 + w4 * 16, k0 = kc * 64;
    const int sr = tid >> 2, scs = (tid & 3) * 16;
    float am[4][4] = {};
    uint4 kreg0, kreg1;
    bf16x8 qhc0, qhc1, qhn0, qhn1;
#define LOAD_K(h_)                                                            \
    {                                                                         \
      size_t krow = (size_t)(b * T_ + k0 + sr) * 2048 + 1024 + (h_) * DH_ + scs; \
      kreg0 = *(const uint4*)&QK[krow];                                       \
      kreg1 = *(const uint4*)&QK[krow + 8];                                   \
    }
#define LOAD_Q(h_, d0, d1)                                                    \
    {                                                                         \
      size_t qoff = (size_t)(b * T_ + q0 + l15) * 2048 + (h_) * DH_;          \
      d0 = *(const bf16x8*)&QK[qoff + 8 * g];                                 \
      d1 = *(const bf16x8*)&QK[qoff + 32 + 8 * g];                            \
    }
    LOAD_K(0);
    LOAD_Q(0, qhc0, qhc1);
#pragma unroll 1
    for (int h = 0; h < H_; h++) {
      *(uint4*)&Kh_s[sr][scs]     = kreg0;
      *(uint4*)&Kh_s[sr][scs + 8] = kreg1;
      __syncthreads();
      if (h < 15) { LOAD_K(h + 1); LOAD_Q(h + 1, qhn0, qhn1); }
      f32x4 accs[4];
#pragma unroll
      for (int mf = 0; mf < 4; mf++) {
        accs[mf][0] = 0.f; accs[mf][1] = 0.f; accs[mf][2] = 0.f; accs[mf][3] = 0.f;
      }
#pragma unroll
      for (int mf = 0; mf < 4; mf++) {
        bf16x8 kh0 = *(bf16x8*)&Kh_s[mf * 16 + l15][8 * g];
        bf16x8 kh1 = *(bf16x8*)&Kh_s[mf * 16 + l15][32 + 8 * g];
        accs[mf] = __builtin_amdgcn_mfma_f32_16x16x32_bf16(kh0, qhc0, accs[mf], 0, 0, 0);
        accs[mf] = __builtin_amdgcn_mfma_f32_16x16x32_bf16(kh1, qhc1, accs[mf], 0, 0, 0);
      }
      const float mq = mrow[(b * H_ + h) * T_ + q0 + l15];
      const float li = linv[(b * H_ + h) * T_ + q0 + l15];
#pragma unroll
      for (int mf = 0; mf < 4; mf++)
#pragma unroll
        for (int r = 0; r < 4; r++)
          am[mf][r] += __builtin_amdgcn_exp2f(accs[mf][r] - mq) * li;
      __syncthreads();
      qhc0 = qhn0; qhc1 = qhn1;
    }
#undef LOAD_K
#undef LOAD_Q
    const float inv16 = 1.0f / 16.0f;
#pragma unroll
    for (int mf = 0; mf < 4; mf++) {
      float4 o;
      o.x = am[mf][0] * inv16; o.y = am[mf][1] * inv16;
      o.z = am[mf][2] * inv16; o.w = am[mf][3] * inv16;
      *(float4*)&am_out[(size_t)(b * T_ + q0 + l15) * T_ + k0 + 16 * mf + 4 * g] = o;
    }
  }
}

// ---------------------------------------------------------------------------
extern "C" void kernel_launch(void* const* d_in, const int* in_sizes, int n_in,
                              void* d_out, int out_size, void* d_ws, size_t ws_size,
                              hipStream_t stream) {
  const float* x  = (const float*)d_in[0];
  const float* Wq = (const float*)d_in[1];
  const float* bq = (const float*)d_in[2];
  const float* Wk = (const float*)d_in[3];
  const float* bk = (const float*)d_in[4];
  const float* Wv = (const float*)d_in[5];
  const float* bv = (const float*)d_in[6];
  const float* Wo = (const float*)d_in[7];
  const float* bo = (const float*)d_in[8];

  float* out = (float*)d_out;                      // [B,T,D]
  float* am  = out + (size_t)B_ * T_ * D_;         // [B,T,T]

  char* w = (char*)d_ws;
  u16* QK    = (u16*)w; w += (size_t)4096 * 2048 * 2;  // Q (pre-scaled) | K
  u16* Vt    = (u16*)w; w += (size_t)64 * 4096 * 2;
  u16* xhi   = (u16*)w; w += (size_t)4096 * 1024 * 2;  // x-hi, then out_pre hi
  u16* WcThi = (u16*)w; w += (size_t)NCAT * 1024 * 2;
  u16* WoThi = (u16*)w; w += (size_t)1024 * 1024 * 2;
  float* mrow  = (float*)w; w += (size_t)B_ * H_ * T_ * 4;
  float* linvp = (float*)w; w += (size_t)B_ * H_ * T_ * 4;
  float* bcat  = (float*)w; w += (size_t)NCAT * 4;

  prep<<<2833, 256, 0, stream>>>(x, Wq, Wk, Wv, Wo, bq, bk, bv,
                                 xhi, WcThi, WoThi, bcat);

  // QKV GEMM (1-pass, BK=32, 2-barrier, XCD-swizzled) -> QK, Vt
  mfma_gemm_qkv<<<544, 256, 0, stream>>>(xhi, WcThi, bcat, QK, Vt);

  attn_fused_mfma<<<512, 512, 0, stream>>>(QK, Vt, mrow, linvp, xhi);

  // tail: Wo GEMM + attn_mean fused in one launch (independent halves)
  tail<<<1536, 256, 0, stream>>>(xhi, WoThi, bo, out, QK, mrow, linvp, am);
}

// Round 24
// 127.460 us; speedup vs baseline: 1.1623x; 1.0390x over previous
//
#include <hip/hip_runtime.h>
#include <math.h>

#define B_ 4
#define T_ 1024
#define D_ 1024
#define H_ 16
#define DH_ 64
#define NCAT 2112   // 1024 (Q) + 1024 (K) + 64 (V)

typedef unsigned short u16;
typedef unsigned int u32;
typedef __attribute__((ext_vector_type(8))) short bf16x8;
typedef __attribute__((ext_vector_type(4))) float f32x4;

// log2-domain score scale: DH^-0.5 * log2(e)  (pre-folded into Q at GEMM)
#define SCALE2 0.18033688f
#define LSTR 72   // LDS row stride in u16: 144 B = 9*16 B (aligned, 2-way banks)

__device__ __forceinline__ u16 bf16rne(float f) {
  u32 u = __float_as_uint(f);
  u32 r = (u + 0x7fffu + ((u >> 16) & 1u)) >> 16;
  return (u16)r;
}
__device__ __forceinline__ float bf16tof(u16 h) {
  return __uint_as_float((u32)h << 16);
}
// pack 2 f32 -> 2 bf16 in one instr (T12 recipe; P-pack only)
__device__ __forceinline__ u32 cvtpk(float lo, float hi) {
  u32 r;
  asm("v_cvt_pk_bf16_f32 %0, %1, %2" : "=v"(r) : "v"(lo), "v"(hi));
  return r;
}

// async global->LDS, 16B per lane; LDS dest = wave-uniform base + lane*16
__device__ __forceinline__ void gload_lds16(const u16* g, u16* l) {
  __builtin_amdgcn_global_load_lds(
      (const __attribute__((address_space(1))) unsigned int*)g,
      (__attribute__((address_space(3))) unsigned int*)l, 16, 0, 0);
}

// ---------------------------------------------------------------------------
// prep: x bf16-round (blocks 0..2047) + weight transposes/round + bias concat
// (blocks 2048..2832) in ONE launch.
// ---------------------------------------------------------------------------
__global__ __launch_bounds__(256) void prep(
    const float* __restrict__ x,
    const float* __restrict__ Wq, const float* __restrict__ Wk,
    const float* __restrict__ Wv, const float* __restrict__ Wo,
    const float* __restrict__ bq, const float* __restrict__ bk,
    const float* __restrict__ bv,
    u16* __restrict__ xhi,
    u16* __restrict__ WcThi, u16* __restrict__ WoThi,
    float* __restrict__ bcat) {
  __shared__ float Ws[64][65];
  const int t = threadIdx.x;
  if (blockIdx.x < 2048) {  // rowconv part
    size_t i = ((size_t)blockIdx.x * 256 + t) * 8;
    float4 v0 = *(const float4*)&x[i];
    float4 v1 = *(const float4*)&x[i + 4];
    float vv[8] = {v0.x, v0.y, v0.z, v0.w, v1.x, v1.y, v1.z, v1.w};
    u32 uh[4];
#pragma unroll
    for (int j = 0; j < 4; j++)
      uh[j] = (u32)bf16rne(vv[2 * j]) | ((u32)bf16rne(vv[2 * j + 1]) << 16);
    *(uint4*)&xhi[i] = make_uint4(uh[0], uh[1], uh[2], uh[3]);
    return;
  }
  const int blk = blockIdx.x - 2048;
  if (blk == 784) {
    for (int i = t; i < NCAT; i += 256)
      bcat[i] = (i < 1024) ? bq[i] : ((i < 2048) ? bk[i - 1024] : bv[i - 2048]);
    return;
  }
  const float* W;
  u16* Thi;
  int roff, Nw, bx, by;
  if (blk < 256)      { W = Wq; Thi = WcThi; roff = 0;    Nw = 1024; bx = blk & 15;         by = blk >> 4; }
  else if (blk < 512) { W = Wk; Thi = WcThi; roff = 1024; Nw = 1024; bx = (blk - 256) & 15; by = (blk - 256) >> 4; }
  else if (blk < 768) { W = Wo; Thi = WoThi; roff = 0;    Nw = 1024; bx = (blk - 512) & 15; by = (blk - 512) >> 4; }
  else                { W = Wv; Thi = WcThi; roff = 2048; Nw = 64;   bx = 0;                by = blk - 768; }

  const int n0 = bx * 64, k0 = by * 64;
#pragma unroll
  for (int rr = 0; rr < 4; rr++) {
    int r = rr * 16 + (t >> 4);
    int c = (t & 15) * 4;
    float4 v = *(const float4*)&W[(size_t)(k0 + r) * Nw + n0 + c];
    Ws[r][c] = v.x; Ws[r][c + 1] = v.y; Ws[r][c + 2] = v.z; Ws[r][c + 3] = v.w;
  }
  __syncthreads();
  const int n = t >> 2, kc = t & 3;
  u32 uh[8];
#pragma unroll
  for (int j2 = 0; j2 < 8; j2++) {
    u16 h0 = bf16rne(Ws[kc * 16 + j2 * 2 + 0][n]);
    u16 h1 = bf16rne(Ws[kc * 16 + j2 * 2 + 1][n]);
    uh[j2] = (u32)h0 | ((u32)h1 << 16);
  }
  size_t base = (size_t)(roff + n0 + n) * 1024 + k0 + kc * 16;
  *(uint4*)&Thi[base]     = make_uint4(uh[0], uh[1], uh[2], uh[3]);
  *(uint4*)&Thi[base + 8] = make_uint4(uh[4], uh[5], uh[6], uh[7]);
}

// ---------------------------------------------------------------------------
// QKV bf16 MFMA GEMM, 1-pass, BK=32, 8 WAVES (512 thr): 128 x 128 tile,
// waves 4x2, each owns 32x64 (MF=2). Per-thread staging halves vs 4-wave;
// waves/CU doubles (same grid) -> barrier drain hidden (r18 mechanism).
// m97 staging (global_load_lds 16B, linear LDS), 2-barrier loop,
// bijective XCD swizzle. mfma(B,A) -> D[n][m].
// Q pre-scaled by SCALE2 -> QK; K -> QK; V -> Vt transposed.
// ---------------------------------------------------------------------------
__global__ __launch_bounds__(512) void mfma_gemm_qkv(
    const u16* __restrict__ Ahi, const u16* __restrict__ Bhi,
    const float* __restrict__ bias,
    u16* __restrict__ QK, u16* __restrict__ Vt) {
  __shared__ u16 Ah[128][32];
  __shared__ u16 Bh[128][32];
  const int tid = threadIdx.x;
  const int lane = tid & 63, wid = tid >> 6;    // 8 waves
  const int wr = wid >> 1, wc = wid & 1;        // 4x2 wave grid
  const int nb8 = 544 >> 3;
  const int swz = (blockIdx.x & 7) * nb8 + (blockIdx.x >> 3);
  const int m0 = (swz % 32) * 128, n0 = (swz / 32) * 128;
  const int Kd = 1024, Nvalid = NCAT;
  f32x4 acc[2][4];
#pragma unroll
  for (int i = 0; i < 2; i++)
#pragma unroll
    for (int j = 0; j < 4; j++) {
      acc[i][j][0] = 0.f; acc[i][j][1] = 0.f;
      acc[i][j][2] = 0.f; acc[i][j][3] = 0.f;
    }
  const int fo = 8 * (lane >> 4);
  const int fr = lane & 15;
  const int srow = lane >> 2;        // row within a 16-row chunk
  const int scol = (lane & 3) * 8;   // u16 col within BK=32

#pragma unroll 1
  for (int k0 = 0; k0 < Kd; k0 += 32) {
    {  // A: 128x32 = 8 chunks of 16 rows; wave wid stages chunk wid
      size_t ga = (size_t)(m0 + wid * 16 + srow) * Kd + k0 + scol;
      gload_lds16(&Ahi[ga], ((u16*)Ah) + wid * 512);
      int grow = n0 + wid * 16 + srow;
      if (grow >= Nvalid) grow = Nvalid - 1;   // clamp; epilogue masks
      size_t gb = (size_t)grow * Kd + k0 + scol;
      gload_lds16(&Bhi[gb], ((u16*)Bh) + wid * 512);
    }
    __syncthreads();
    bf16x8 bhf[4];
#pragma unroll
    for (int nf = 0; nf < 4; nf++) {
      int r = wc * 64 + nf * 16 + fr;
      bhf[nf] = *(bf16x8*)&Bh[r][fo];
    }
#pragma unroll
    for (int mf = 0; mf < 2; mf++) {
      int r = wr * 32 + mf * 16 + fr;
      bf16x8 ahf = *(bf16x8*)&Ah[r][fo];
#pragma unroll
      for (int nf = 0; nf < 4; nf++)
        acc[mf][nf] = __builtin_amdgcn_mfma_f32_16x16x32_bf16(bhf[nf], ahf, acc[mf][nf], 0, 0, 0);
    }
    __syncthreads();
  }
  const int rq = lane >> 4;
#pragma unroll
  for (int mf = 0; mf < 2; mf++) {
    int m = m0 + wr * 32 + mf * 16 + fr;
#pragma unroll
    for (int nf = 0; nf < 4; nf++) {
      int nb = n0 + wc * 64 + nf * 16 + rq * 4;
      if (nb < Nvalid) {
        float4 b4 = *(const float4*)&bias[nb];
        float v0 = acc[mf][nf][0] + b4.x;
        float v1 = acc[mf][nf][1] + b4.y;
        float v2 = acc[mf][nf][2] + b4.z;
        float v3 = acc[mf][nf][3] + b4.w;
        if (nb < 1024) {               // Q: pre-scaled by SCALE2
          v0 *= SCALE2; v1 *= SCALE2; v2 *= SCALE2; v3 *= SCALE2;
          *(uint2*)&QK[(size_t)m * 2048 + nb] =
              make_uint2((u32)bf16rne(v0) | ((u32)bf16rne(v1) << 16),
                         (u32)bf16rne(v2) | ((u32)bf16rne(v3) << 16));
        } else if (nb < 2048) {        // K: plain bf16
          *(uint2*)&QK[(size_t)m * 2048 + nb] =
              make_uint2((u32)bf16rne(v0) | ((u32)bf16rne(v1) << 16),
                         (u32)bf16rne(v2) | ((u32)bf16rne(v3) << 16));
        } else {                       // V: transposed; contiguous in m
          Vt[(size_t)(nb - 2048 + 0) * 4096 + m] = bf16rne(v0);
          Vt[(size_t)(nb - 2048 + 1) * 4096 + m] = bf16rne(v1);
          Vt[(size_t)(nb - 2048 + 2) * 4096 + m] = bf16rne(v2);
          Vt[(size_t)(nb - 2048 + 3) * 4096 + m] = bf16rne(v3);
        }
      }
    }
  }
}

// ---------------------------------------------------------------------------
// MFMA flash attention, 8 WAVES (512 thr), 128 q rows/block.
// grid = B*H*(T/128) = 512 (XCD-swizzled). Single-buffer K/V LDS +
// async-split. Q pre-scaled -> S log2-domain. Defer-max THR=8.
// setprio around MFMA. PV swapped: mfma(V, P) -> O[d][q=l15].
// ---------------------------------------------------------------------------
__global__ __launch_bounds__(512) void attn_fused_mfma(
    const u16* __restrict__ QK, const u16* __restrict__ Vt,
    float* __restrict__ mrow, float* __restrict__ linv,
    u16* __restrict__ ophi) {
  __shared__ u16 Kh_s[64][LSTR];
  __shared__ u16 Vt_s[64][LSTR];
  __shared__ u16 P_s[8][16][LSTR];
  const int bi0 = blockIdx.x;
  const int bi = (bi0 & 7) * 64 + (bi0 >> 3);   // XCD swizzle (512 = 8*64)
  const int qt = bi & 7, h = (bi >> 3) & 15, b = bi >> 7;
  const int tid = threadIdx.x;
  const int lane = tid & 63, w = tid >> 6;      // 8 waves
  const int l15 = lane & 15, g = lane >> 4;
  const int q0 = qt * 128 + w * 16;
  const int sr = tid >> 3, scs = (tid & 7) * 8; // staging: 1 uint4/thread/array
  bf16x8 qh[2];
  {
    size_t qoff = (size_t)(b * T_ + q0 + l15) * 2048 + h * DH_;
    qh[0] = *(const bf16x8*)&QK[qoff + 8 * g];
    qh[1] = *(const bf16x8*)&QK[qoff + 32 + 8 * g];
  }
  float m_run = -1e30f, l_run = 0.f;
  f32x4 acc_o[4];
#pragma unroll
  for (int nf = 0; nf < 4; nf++) {
    acc_o[nf][0] = 0.f; acc_o[nf][1] = 0.f; acc_o[nf][2] = 0.f; acc_o[nf][3] = 0.f;
  }

  uint4 kreg, vreg;
#define LOAD_TILE(kt_)                                                        \
  {                                                                           \
    kreg = *(const uint4*)&QK[(size_t)(b * T_ + (kt_) * 64 + sr) * 2048 + 1024 + h * DH_ + scs]; \
    vreg = *(const uint4*)&Vt[(size_t)sr * 4096 + b * T_ + (kt_) * 64 + scs]; \
  }
#define STORE_TILE()                                                          \
  {                                                                           \
    *(uint4*)&Kh_s[sr][scs] = kreg;                                           \
    *(uint4*)&Vt_s[sr][scs] = vreg;                                           \
  }

  LOAD_TILE(0);

#pragma unroll 1
  for (int kt = 0; kt < 16; kt++) {
    STORE_TILE();
    __syncthreads();
    if (kt < 15) LOAD_TILE(kt + 1);
    f32x4 accs[4];
#pragma unroll
    for (int mf = 0; mf < 4; mf++) {
      accs[mf][0] = 0.f; accs[mf][1] = 0.f; accs[mf][2] = 0.f; accs[mf][3] = 0.f;
    }
    __builtin_amdgcn_s_setprio(1);
#pragma unroll
    for (int mf = 0; mf < 4; mf++) {
#pragma unroll
      for (int ks = 0; ks < 2; ks++) {
        bf16x8 kh = *(bf16x8*)&Kh_s[mf * 16 + l15][ks * 32 + 8 * g];
        accs[mf] = __builtin_amdgcn_mfma_f32_16x16x32_bf16(kh, qh[ks], accs[mf], 0, 0, 0);
      }
    }
    __builtin_amdgcn_s_setprio(0);
    float t0 = fmaxf(fmaxf(accs[0][0], accs[0][1]), fmaxf(accs[0][2], accs[0][3]));
    float t1 = fmaxf(fmaxf(accs[1][0], accs[1][1]), fmaxf(accs[1][2], accs[1][3]));
    float t2 = fmaxf(fmaxf(accs[2][0], accs[2][1]), fmaxf(accs[2][2], accs[2][3]));
    float t3 = fmaxf(fmaxf(accs[3][0], accs[3][1]), fmaxf(accs[3][2], accs[3][3]));
    float tm = fmaxf(fmaxf(t0, t1), fmaxf(t2, t3));
    tm = fmaxf(tm, __shfl_xor(tm, 16));
    tm = fmaxf(tm, __shfl_xor(tm, 32));
    if (!__all(tm <= m_run + 8.f)) {
      float m_new = fmaxf(m_run, tm);
      float crs = __builtin_amdgcn_exp2f(m_run - m_new);
      l_run *= crs;
#pragma unroll
      for (int nf = 0; nf < 4; nf++)
#pragma unroll
        for (int r = 0; r < 4; r++) acc_o[nf][r] *= crs;
      m_run = m_new;
    }
    float ts = 0.f;
#pragma unroll
    for (int mf = 0; mf < 4; mf++) {
      float p0 = __builtin_amdgcn_exp2f(accs[mf][0] - m_run);
      float p1 = __builtin_amdgcn_exp2f(accs[mf][1] - m_run);
      float p2 = __builtin_amdgcn_exp2f(accs[mf][2] - m_run);
      float p3 = __builtin_amdgcn_exp2f(accs[mf][3] - m_run);
      ts += (p0 + p1) + (p2 + p3);
      *(uint2*)&P_s[w][l15][16 * mf + 4 * g] =
          make_uint2(cvtpk(p0, p1), cvtpk(p2, p3));
    }
    ts += __shfl_xor(ts, 16);
    ts += __shfl_xor(ts, 32);
    l_run += ts;
    bf16x8 pa[2];
    pa[0] = *(bf16x8*)&P_s[w][l15][8 * g];
    pa[1] = *(bf16x8*)&P_s[w][l15][32 + 8 * g];
    __builtin_amdgcn_s_setprio(1);
#pragma unroll
    for (int nf = 0; nf < 4; nf++) {
#pragma unroll
      for (int ks = 0; ks < 2; ks++) {
        bf16x8 vb = *(bf16x8*)&Vt_s[nf * 16 + l15][ks * 32 + 8 * g];
        acc_o[nf] = __builtin_amdgcn_mfma_f32_16x16x32_bf16(vb, pa[ks], acc_o[nf], 0, 0, 0);
      }
    }
    __builtin_amdgcn_s_setprio(0);
    __syncthreads();
  }
#undef LOAD_TILE
#undef STORE_TILE
  float li = 1.0f / l_run;
  if (g == 0) {
    int idx = (b * H_ + h) * T_ + q0 + l15;
    mrow[idx] = m_run;
    linv[idx] = li;
  }
  size_t obase = (size_t)(b * T_ + q0 + l15) * D_ + h * DH_;
#pragma unroll
  for (int nf = 0; nf < 4; nf++) {
    float v0 = acc_o[nf][0] * li, v1 = acc_o[nf][1] * li;
    float v2 = acc_o[nf][2] * li, v3 = acc_o[nf][3] * li;
    *(uint2*)&ophi[obase + nf * 16 + 4 * g] =
        make_uint2((u32)bf16rne(v0) | ((u32)bf16rne(v1) << 16),
                   (u32)bf16rne(v2) | ((u32)bf16rne(v3) << 16));
  }
}

// ---------------------------------------------------------------------------
// tail: Wo GEMM (blocks 0..511) + attn_mean 4-wave (blocks 512..1535) in ONE
// launch — the two are independent (both depend only on attn_fused) and
// co-schedule across CUs. 256 threads; 12 KB shared pool aliased by branch.
// ---------------------------------------------------------------------------
__global__ __launch_bounds__(256) void tail(
    const u16* __restrict__ xhi, const u16* __restrict__ WoThi,
    const float* __restrict__ bo, float* __restrict__ out,
    const u16* __restrict__ QK, const float* __restrict__ mrow,
    const float* __restrict__ linv, float* __restrict__ am_out) {
  __shared__ u16 pool[64 * 32 + 128 * 32];  // 12 KB
  const int tid = threadIdx.x;
  const int lane = tid & 63, w4 = tid >> 6;
  const int l15 = lane & 15, g = lane >> 4;

  if (blockIdx.x < 512) {
    // ---- Wo GEMM: TM=64, 128-wide N tile, BK=32, 2-barrier, XCD swizzle ----
    u16(*Ah)[32] = (u16(*)[32])pool;             // [64][32]
    u16(*Bh)[32] = (u16(*)[32])(pool + 64 * 32); // [128][32]
    const int wr = w4 >> 1, wc = w4 & 1;
    const int swz = ((int)blockIdx.x & 7) * 64 + ((int)blockIdx.x >> 3);
    const int m0 = (swz % 64) * 64, n0 = (swz / 64) * 128;
    const int Kd = 1024;
    f32x4 acc[2][4];
#pragma unroll
    for (int i = 0; i < 2; i++)
#pragma unroll
      for (int j = 0; j < 4; j++) {
        acc[i][j][0] = 0.f; acc[i][j][1] = 0.f;
        acc[i][j][2] = 0.f; acc[i][j][3] = 0.f;
      }
    const int fo = 8 * g;
    const int fr = l15;
    const int srow = lane >> 2;
    const int scol = (lane & 3) * 8;
#pragma unroll 1
    for (int k0 = 0; k0 < Kd; k0 += 32) {
      {
        int chunk = w4;  // A: 64x32 = 4 chunks, 1 per wave
        size_t ga = (size_t)(m0 + chunk * 16 + srow) * Kd + k0 + scol;
        gload_lds16(&xhi[ga], ((u16*)Ah) + chunk * 512);
      }
#pragma unroll
      for (int c = 0; c < 2; c++) {
        int chunk = w4 * 2 + c;  // B: 128x32 = 8 chunks
        size_t gb = (size_t)(n0 + chunk * 16 + srow) * Kd + k0 + scol;
        gload_lds16(&WoThi[gb], ((u16*)Bh) + chunk * 512);
      }
      __syncthreads();
      bf16x8 bhf[4];
#pragma unroll
      for (int nf = 0; nf < 4; nf++) {
        int r = wc * 64 + nf * 16 + fr;
        bhf[nf] = *(bf16x8*)&Bh[r][fo];
      }
#pragma unroll
      for (int mf = 0; mf < 2; mf++) {
        int r = wr * 32 + mf * 16 + fr;
        bf16x8 ahf = *(bf16x8*)&Ah[r][fo];
#pragma unroll
        for (int nf = 0; nf < 4; nf++)
          acc[mf][nf] = __builtin_amdgcn_mfma_f32_16x16x32_bf16(bhf[nf], ahf, acc[mf][nf], 0, 0, 0);
      }
      __syncthreads();
    }
    const int rq = g;
#pragma unroll
    for (int mf = 0; mf < 2; mf++) {
      int m = m0 + wr * 32 + mf * 16 + fr;
#pragma unroll
      for (int nf = 0; nf < 4; nf++) {
        int nb = n0 + wc * 64 + nf * 16 + rq * 4;
        float4 b4 = *(const float4*)&bo[nb];
        float4 o;
        o.x = acc[mf][nf][0] + b4.x;
        o.y = acc[mf][nf][1] + b4.y;
        o.z = acc[mf][nf][2] + b4.z;
        o.w = acc[mf][nf][3] + b4.w;
        *(float4*)&out[(size_t)m * 1024 + nb] = o;
      }
    }
  } else {
    // ---- attn_mean: 4-wave, 64 q rows x 64 k cols, 16-head loop ----
    u16(*Kh_s)[LSTR] = (u16(*)[LSTR])pool;  // [64][72] = 9.2 KB < 12 KB
    const int bi0 = (int)blockIdx.x - 512;
    const int bi = (bi0 & 7) * 128 + (bi0 >> 3);  // XCD swizzle (1024 = 8*128)
    const int kc = bi & 15, qt = (bi >> 4) & 15, b = bi >> 8;
    const int q0 = qt * 64 + w4 * 16, k0 = kc * 64;
    const int sr = tid >> 2, scs = (tid & 3) * 16;
    float am[4][4] = {};
    uint4 kreg0, kreg1;
    bf16x8 qhc0, qhc1, qhn0, qhn1;
#define LOAD_K(h_)                                                            \
    {                                                                         \
      size_t krow = (size_t)(b * T_ + k0 + sr) * 2048 + 1024 + (h_) * DH_ + scs; \
      kreg0 = *(const uint4*)&QK[krow];                                       \
      kreg1 = *(const uint4*)&QK[krow + 8];                                   \
    }
#define LOAD_Q(h_, d0, d1)                                                    \
    {                                                                         \
      size_t qoff = (size_t)(b * T_ + q0 + l15) * 2048 + (h_) * DH_;          \
      d0 = *(const bf16x8*)&QK[qoff + 8 * g];                                 \
      d1 = *(const bf16x8*)&QK[qoff + 32 + 8 * g];                            \
    }
    LOAD_K(0);
    LOAD_Q(0, qhc0, qhc1);
#pragma unroll 1
    for (int h = 0; h < H_; h++) {
      *(uint4*)&Kh_s[sr][scs]     = kreg0;
      *(uint4*)&Kh_s[sr][scs + 8] = kreg1;
      __syncthreads();
      if (h < 15) { LOAD_K(h + 1); LOAD_Q(h + 1, qhn0, qhn1); }
      f32x4 accs[4];
#pragma unroll
      for (int mf = 0; mf < 4; mf++) {
        accs[mf][0] = 0.f; accs[mf][1] = 0.f; accs[mf][2] = 0.f; accs[mf][3] = 0.f;
      }
#pragma unroll
      for (int mf = 0; mf < 4; mf++) {
        bf16x8 kh0 = *(bf16x8*)&Kh_s[mf * 16 + l15][8 * g];
        bf16x8 kh1 = *(bf16x8*)&Kh_s[mf * 16 + l15][32 + 8 * g];
        accs[mf] = __builtin_amdgcn_mfma_f32_16x16x32_bf16(kh0, qhc0, accs[mf], 0, 0, 0);
        accs[mf] = __builtin_amdgcn_mfma_f32_16x16x32_bf16(kh1, qhc1, accs[mf], 0, 0, 0);
      }
      const float mq = mrow[(b * H_ + h) * T_ + q0 + l15];
      const float li = linv[(b * H_ + h) * T_ + q0 + l15];
#pragma unroll
      for (int mf = 0; mf < 4; mf++)
#pragma unroll
        for (int r = 0; r < 4; r++)
          am[mf][r] += __builtin_amdgcn_exp2f(accs[mf][r] - mq) * li;
      __syncthreads();
      qhc0 = qhn0; qhc1 = qhn1;
    }
#undef LOAD_K
#undef LOAD_Q
    const float inv16 = 1.0f / 16.0f;
#pragma unroll
    for (int mf = 0; mf < 4; mf++) {
      float4 o;
      o.x = am[mf][0] * inv16; o.y = am[mf][1] * inv16;
      o.z = am[mf][2] * inv16; o.w = am[mf][3] * inv16;
      *(float4*)&am_out[(size_t)(b * T_ + q0 + l15) * T_ + k0 + 16 * mf + 4 * g] = o;
    }
  }
}

// ---------------------------------------------------------------------------
extern "C" void kernel_launch(void* const* d_in, const int* in_sizes, int n_in,
                              void* d_out, int out_size, void* d_ws, size_t ws_size,
                              hipStream_t stream) {
  const float* x  = (const float*)d_in[0];
  const float* Wq = (const float*)d_in[1];
  const float* bq = (const float*)d_in[2];
  const float* Wk = (const float*)d_in[3];
  const float* bk = (const float*)d_in[4];
  const float* Wv = (const float*)d_in[5];
  const float* bv = (const float*)d_in[6];
  const float* Wo = (const float*)d_in[7];
  const float* bo = (const float*)d_in[8];

  float* out = (float*)d_out;                      // [B,T,D]
  float* am  = out + (size_t)B_ * T_ * D_;         // [B,T,T]

  char* w = (char*)d_ws;
  u16* QK    = (u16*)w; w += (size_t)4096 * 2048 * 2;  // Q (pre-scaled) | K
  u16* Vt    = (u16*)w; w += (size_t)64 * 4096 * 2;
  u16* xhi   = (u16*)w; w += (size_t)4096 * 1024 * 2;  // x-hi, then out_pre hi
  u16* WcThi = (u16*)w; w += (size_t)NCAT * 1024 * 2;
  u16* WoThi = (u16*)w; w += (size_t)1024 * 1024 * 2;
  float* mrow  = (float*)w; w += (size_t)B_ * H_ * T_ * 4;
  float* linvp = (float*)w; w += (size_t)B_ * H_ * T_ * 4;
  float* bcat  = (float*)w; w += (size_t)NCAT * 4;

  prep<<<2833, 256, 0, stream>>>(x, Wq, Wk, Wv, Wo, bq, bk, bv,
                                 xhi, WcThi, WoThi, bcat);

  // QKV GEMM (1-pass, BK=32, 8-wave, 2-barrier, XCD-swizzled) -> QK, Vt
  mfma_gemm_qkv<<<544, 512, 0, stream>>>(xhi, WcThi, bcat, QK, Vt);

  attn_fused_mfma<<<512, 512, 0, stream>>>(QK, Vt, mrow, linvp, xhi);

  // tail: Wo GEMM + attn_mean fused in one launch (independent halves)
  tail<<<1536, 256, 0, stream>>>(xhi, WoThi, bo, out, QK, mrow, linvp, am);
}

// Round 25
// 115.297 us; speedup vs baseline: 1.2849x; 1.1055x over previous
//
#include <hip/hip_runtime.h>
#include <math.h>

#define B_ 4
#define T_ 1024
#define D_ 1024
#define H_ 16
#define DH_ 64
#define NCAT 2112   // 1024 (Q) + 1024 (K) + 64 (V)

typedef unsigned short u16;
typedef unsigned int u32;
typedef __attribute__((ext_vector_type(8))) short bf16x8;
typedef __attribute__((ext_vector_type(4))) float f32x4;

// log2-domain score scale: DH^-0.5 * log2(e)  (pre-folded into Q at GEMM)
#define SCALE2 0.18033688f
#define LSTR 72   // LDS row stride in u16: 144 B = 9*16 B (aligned, 2-way banks)

__device__ __forceinline__ u16 bf16rne(float f) {
  u32 u = __float_as_uint(f);
  u32 r = (u + 0x7fffu + ((u >> 16) & 1u)) >> 16;
  return (u16)r;
}
__device__ __forceinline__ float bf16tof(u16 h) {
  return __uint_as_float((u32)h << 16);
}
// pack 2 f32 -> 2 bf16 in one instr (T12 recipe; P-pack only)
__device__ __forceinline__ u32 cvtpk(float lo, float hi) {
  u32 r;
  asm("v_cvt_pk_bf16_f32 %0, %1, %2" : "=v"(r) : "v"(lo), "v"(hi));
  return r;
}

// async global->LDS, 16B per lane; LDS dest = wave-uniform base + lane*16
__device__ __forceinline__ void gload_lds16(const u16* g, u16* l) {
  __builtin_amdgcn_global_load_lds(
      (const __attribute__((address_space(1))) unsigned int*)g,
      (__attribute__((address_space(3))) unsigned int*)l, 16, 0, 0);
}

// ---------------------------------------------------------------------------
// prep: x bf16-round (blocks 0..2047) + weight transposes/round + bias concat
// (blocks 2048..2832) in ONE launch.
// ---------------------------------------------------------------------------
__global__ __launch_bounds__(256) void prep(
    const float* __restrict__ x,
    const float* __restrict__ Wq, const float* __restrict__ Wk,
    const float* __restrict__ Wv, const float* __restrict__ Wo,
    const float* __restrict__ bq, const float* __restrict__ bk,
    const float* __restrict__ bv,
    u16* __restrict__ xhi,
    u16* __restrict__ WcThi, u16* __restrict__ WoThi,
    float* __restrict__ bcat) {
  __shared__ float Ws[64][65];
  const int t = threadIdx.x;
  if (blockIdx.x < 2048) {  // rowconv part
    size_t i = ((size_t)blockIdx.x * 256 + t) * 8;
    float4 v0 = *(const float4*)&x[i];
    float4 v1 = *(const float4*)&x[i + 4];
    float vv[8] = {v0.x, v0.y, v0.z, v0.w, v1.x, v1.y, v1.z, v1.w};
    u32 uh[4];
#pragma unroll
    for (int j = 0; j < 4; j++)
      uh[j] = (u32)bf16rne(vv[2 * j]) | ((u32)bf16rne(vv[2 * j + 1]) << 16);
    *(uint4*)&xhi[i] = make_uint4(uh[0], uh[1], uh[2], uh[3]);
    return;
  }
  const int blk = blockIdx.x - 2048;
  if (blk == 784) {
    for (int i = t; i < NCAT; i += 256)
      bcat[i] = (i < 1024) ? bq[i] : ((i < 2048) ? bk[i - 1024] : bv[i - 2048]);
    return;
  }
  const float* W;
  u16* Thi;
  int roff, Nw, bx, by;
  if (blk < 256)      { W = Wq; Thi = WcThi; roff = 0;    Nw = 1024; bx = blk & 15;         by = blk >> 4; }
  else if (blk < 512) { W = Wk; Thi = WcThi; roff = 1024; Nw = 1024; bx = (blk - 256) & 15; by = (blk - 256) >> 4; }
  else if (blk < 768) { W = Wo; Thi = WoThi; roff = 0;    Nw = 1024; bx = (blk - 512) & 15; by = (blk - 512) >> 4; }
  else                { W = Wv; Thi = WcThi; roff = 2048; Nw = 64;   bx = 0;                by = blk - 768; }

  const int n0 = bx * 64, k0 = by * 64;
#pragma unroll
  for (int rr = 0; rr < 4; rr++) {
    int r = rr * 16 + (t >> 4);
    int c = (t & 15) * 4;
    float4 v = *(const float4*)&W[(size_t)(k0 + r) * Nw + n0 + c];
    Ws[r][c] = v.x; Ws[r][c + 1] = v.y; Ws[r][c + 2] = v.z; Ws[r][c + 3] = v.w;
  }
  __syncthreads();
  const int n = t >> 2, kc = t & 3;
  u32 uh[8];
#pragma unroll
  for (int j2 = 0; j2 < 8; j2++) {
    u16 h0 = bf16rne(Ws[kc * 16 + j2 * 2 + 0][n]);
    u16 h1 = bf16rne(Ws[kc * 16 + j2 * 2 + 1][n]);
    uh[j2] = (u32)h0 | ((u32)h1 << 16);
  }
  size_t base = (size_t)(roff + n0 + n) * 1024 + k0 + kc * 16;
  *(uint4*)&Thi[base]     = make_uint4(uh[0], uh[1], uh[2], uh[3]);
  *(uint4*)&Thi[base + 8] = make_uint4(uh[4], uh[5], uh[6], uh[7]);
}

// ---------------------------------------------------------------------------
// QKV bf16 MFMA GEMM, 1-pass, BK=32, 8 WAVES (512 thr): 128 x 128 tile,
// waves 4x2, each owns 32x64 (MF=2). m97 staging, 2-barrier loop,
// bijective XCD swizzle. mfma(B,A) -> D[n][m].
// Q pre-scaled by SCALE2 -> QK; K -> QK; V -> Vt transposed.
// ---------------------------------------------------------------------------
__global__ __launch_bounds__(512) void mfma_gemm_qkv(
    const u16* __restrict__ Ahi, const u16* __restrict__ Bhi,
    const float* __restrict__ bias,
    u16* __restrict__ QK, u16* __restrict__ Vt) {
  __shared__ u16 Ah[128][32];
  __shared__ u16 Bh[128][32];
  const int tid = threadIdx.x;
  const int lane = tid & 63, wid = tid >> 6;    // 8 waves
  const int wr = wid >> 1, wc = wid & 1;        // 4x2 wave grid
  const int nb8 = 544 >> 3;
  const int swz = (blockIdx.x & 7) * nb8 + (blockIdx.x >> 3);
  const int m0 = (swz % 32) * 128, n0 = (swz / 32) * 128;
  const int Kd = 1024, Nvalid = NCAT;
  f32x4 acc[2][4];
#pragma unroll
  for (int i = 0; i < 2; i++)
#pragma unroll
    for (int j = 0; j < 4; j++) {
      acc[i][j][0] = 0.f; acc[i][j][1] = 0.f;
      acc[i][j][2] = 0.f; acc[i][j][3] = 0.f;
    }
  const int fo = 8 * (lane >> 4);
  const int fr = lane & 15;
  const int srow = lane >> 2;        // row within a 16-row chunk
  const int scol = (lane & 3) * 8;   // u16 col within BK=32

#pragma unroll 1
  for (int k0 = 0; k0 < Kd; k0 += 32) {
    {  // A/B: 128x32 = 8 chunks of 16 rows; wave wid stages chunk wid
      size_t ga = (size_t)(m0 + wid * 16 + srow) * Kd + k0 + scol;
      gload_lds16(&Ahi[ga], ((u16*)Ah) + wid * 512);
      int grow = n0 + wid * 16 + srow;
      if (grow >= Nvalid) grow = Nvalid - 1;   // clamp; epilogue masks
      size_t gb = (size_t)grow * Kd + k0 + scol;
      gload_lds16(&Bhi[gb], ((u16*)Bh) + wid * 512);
    }
    __syncthreads();
    bf16x8 bhf[4];
#pragma unroll
    for (int nf = 0; nf < 4; nf++) {
      int r = wc * 64 + nf * 16 + fr;
      bhf[nf] = *(bf16x8*)&Bh[r][fo];
    }
#pragma unroll
    for (int mf = 0; mf < 2; mf++) {
      int r = wr * 32 + mf * 16 + fr;
      bf16x8 ahf = *(bf16x8*)&Ah[r][fo];
#pragma unroll
      for (int nf = 0; nf < 4; nf++)
        acc[mf][nf] = __builtin_amdgcn_mfma_f32_16x16x32_bf16(bhf[nf], ahf, acc[mf][nf], 0, 0, 0);
    }
    __syncthreads();
  }
  const int rq = lane >> 4;
#pragma unroll
  for (int mf = 0; mf < 2; mf++) {
    int m = m0 + wr * 32 + mf * 16 + fr;
#pragma unroll
    for (int nf = 0; nf < 4; nf++) {
      int nb = n0 + wc * 64 + nf * 16 + rq * 4;
      if (nb < Nvalid) {
        float4 b4 = *(const float4*)&bias[nb];
        float v0 = acc[mf][nf][0] + b4.x;
        float v1 = acc[mf][nf][1] + b4.y;
        float v2 = acc[mf][nf][2] + b4.z;
        float v3 = acc[mf][nf][3] + b4.w;
        if (nb < 1024) {               // Q: pre-scaled by SCALE2
          v0 *= SCALE2; v1 *= SCALE2; v2 *= SCALE2; v3 *= SCALE2;
          *(uint2*)&QK[(size_t)m * 2048 + nb] =
              make_uint2((u32)bf16rne(v0) | ((u32)bf16rne(v1) << 16),
                         (u32)bf16rne(v2) | ((u32)bf16rne(v3) << 16));
        } else if (nb < 2048) {        // K: plain bf16
          *(uint2*)&QK[(size_t)m * 2048 + nb] =
              make_uint2((u32)bf16rne(v0) | ((u32)bf16rne(v1) << 16),
                         (u32)bf16rne(v2) | ((u32)bf16rne(v3) << 16));
        } else {                       // V: transposed; contiguous in m
          Vt[(size_t)(nb - 2048 + 0) * 4096 + m] = bf16rne(v0);
          Vt[(size_t)(nb - 2048 + 1) * 4096 + m] = bf16rne(v1);
          Vt[(size_t)(nb - 2048 + 2) * 4096 + m] = bf16rne(v2);
          Vt[(size_t)(nb - 2048 + 3) * 4096 + m] = bf16rne(v3);
        }
      }
    }
  }
}

// ---------------------------------------------------------------------------
// MFMA flash attention, 8 WAVES (512 thr), 128 q rows/block.
// grid = B*H*(T/128) = 512 (XCD-swizzled). Single-buffer K/V LDS +
// async-split. Q pre-scaled -> S log2-domain. Defer-max THR=8.
// setprio around MFMA. PV swapped: mfma(V, P) -> O[d][q=l15].
// ---------------------------------------------------------------------------
__global__ __launch_bounds__(512) void attn_fused_mfma(
    const u16* __restrict__ QK, const u16* __restrict__ Vt,
    float* __restrict__ mrow, float* __restrict__ linv,
    u16* __restrict__ ophi) {
  __shared__ u16 Kh_s[64][LSTR];
  __shared__ u16 Vt_s[64][LSTR];
  __shared__ u16 P_s[8][16][LSTR];
  const int bi0 = blockIdx.x;
  const int bi = (bi0 & 7) * 64 + (bi0 >> 3);   // XCD swizzle (512 = 8*64)
  const int qt = bi & 7, h = (bi >> 3) & 15, b = bi >> 7;
  const int tid = threadIdx.x;
  const int lane = tid & 63, w = tid >> 6;      // 8 waves
  const int l15 = lane & 15, g = lane >> 4;
  const int q0 = qt * 128 + w * 16;
  const int sr = tid >> 3, scs = (tid & 7) * 8; // staging: 1 uint4/thread/array
  bf16x8 qh[2];
  {
    size_t qoff = (size_t)(b * T_ + q0 + l15) * 2048 + h * DH_;
    qh[0] = *(const bf16x8*)&QK[qoff + 8 * g];
    qh[1] = *(const bf16x8*)&QK[qoff + 32 + 8 * g];
  }
  float m_run = -1e30f, l_run = 0.f;
  f32x4 acc_o[4];
#pragma unroll
  for (int nf = 0; nf < 4; nf++) {
    acc_o[nf][0] = 0.f; acc_o[nf][1] = 0.f; acc_o[nf][2] = 0.f; acc_o[nf][3] = 0.f;
  }

  uint4 kreg, vreg;
#define LOAD_TILE(kt_)                                                        \
  {                                                                           \
    kreg = *(const uint4*)&QK[(size_t)(b * T_ + (kt_) * 64 + sr) * 2048 + 1024 + h * DH_ + scs]; \
    vreg = *(const uint4*)&Vt[(size_t)sr * 4096 + b * T_ + (kt_) * 64 + scs]; \
  }
#define STORE_TILE()                                                          \
  {                                                                           \
    *(uint4*)&Kh_s[sr][scs] = kreg;                                           \
    *(uint4*)&Vt_s[sr][scs] = vreg;                                           \
  }

  LOAD_TILE(0);

#pragma unroll 1
  for (int kt = 0; kt < 16; kt++) {
    STORE_TILE();
    __syncthreads();
    if (kt < 15) LOAD_TILE(kt + 1);
    f32x4 accs[4];
#pragma unroll
    for (int mf = 0; mf < 4; mf++) {
      accs[mf][0] = 0.f; accs[mf][1] = 0.f; accs[mf][2] = 0.f; accs[mf][3] = 0.f;
    }
    __builtin_amdgcn_s_setprio(1);
#pragma unroll
    for (int mf = 0; mf < 4; mf++) {
#pragma unroll
      for (int ks = 0; ks < 2; ks++) {
        bf16x8 kh = *(bf16x8*)&Kh_s[mf * 16 + l15][ks * 32 + 8 * g];
        accs[mf] = __builtin_amdgcn_mfma_f32_16x16x32_bf16(kh, qh[ks], accs[mf], 0, 0, 0);
      }
    }
    __builtin_amdgcn_s_setprio(0);
    float t0 = fmaxf(fmaxf(accs[0][0], accs[0][1]), fmaxf(accs[0][2], accs[0][3]));
    float t1 = fmaxf(fmaxf(accs[1][0], accs[1][1]), fmaxf(accs[1][2], accs[1][3]));
    float t2 = fmaxf(fmaxf(accs[2][0], accs[2][1]), fmaxf(accs[2][2], accs[2][3]));
    float t3 = fmaxf(fmaxf(accs[3][0], accs[3][1]), fmaxf(accs[3][2], accs[3][3]));
    float tm = fmaxf(fmaxf(t0, t1), fmaxf(t2, t3));
    tm = fmaxf(tm, __shfl_xor(tm, 16));
    tm = fmaxf(tm, __shfl_xor(tm, 32));
    if (!__all(tm <= m_run + 8.f)) {
      float m_new = fmaxf(m_run, tm);
      float crs = __builtin_amdgcn_exp2f(m_run - m_new);
      l_run *= crs;
#pragma unroll
      for (int nf = 0; nf < 4; nf++)
#pragma unroll
        for (int r = 0; r < 4; r++) acc_o[nf][r] *= crs;
      m_run = m_new;
    }
    float ts = 0.f;
#pragma unroll
    for (int mf = 0; mf < 4; mf++) {
      float p0 = __builtin_amdgcn_exp2f(accs[mf][0] - m_run);
      float p1 = __builtin_amdgcn_exp2f(accs[mf][1] - m_run);
      float p2 = __builtin_amdgcn_exp2f(accs[mf][2] - m_run);
      float p3 = __builtin_amdgcn_exp2f(accs[mf][3] - m_run);
      ts += (p0 + p1) + (p2 + p3);
      *(uint2*)&P_s[w][l15][16 * mf + 4 * g] =
          make_uint2(cvtpk(p0, p1), cvtpk(p2, p3));
    }
    ts += __shfl_xor(ts, 16);
    ts += __shfl_xor(ts, 32);
    l_run += ts;
    bf16x8 pa[2];
    pa[0] = *(bf16x8*)&P_s[w][l15][8 * g];
    pa[1] = *(bf16x8*)&P_s[w][l15][32 + 8 * g];
    __builtin_amdgcn_s_setprio(1);
#pragma unroll
    for (int nf = 0; nf < 4; nf++) {
#pragma unroll
      for (int ks = 0; ks < 2; ks++) {
        bf16x8 vb = *(bf16x8*)&Vt_s[nf * 16 + l15][ks * 32 + 8 * g];
        acc_o[nf] = __builtin_amdgcn_mfma_f32_16x16x32_bf16(vb, pa[ks], acc_o[nf], 0, 0, 0);
      }
    }
    __builtin_amdgcn_s_setprio(0);
    __syncthreads();
  }
#undef LOAD_TILE
#undef STORE_TILE
  float li = 1.0f / l_run;
  if (g == 0) {
    int idx = (b * H_ + h) * T_ + q0 + l15;
    mrow[idx] = m_run;
    linv[idx] = li;
  }
  size_t obase = (size_t)(b * T_ + q0 + l15) * D_ + h * DH_;
#pragma unroll
  for (int nf = 0; nf < 4; nf++) {
    float v0 = acc_o[nf][0] * li, v1 = acc_o[nf][1] * li;
    float v2 = acc_o[nf][2] * li, v3 = acc_o[nf][3] * li;
    *(uint2*)&ophi[obase + nf * 16 + 4 * g] =
        make_uint2((u32)bf16rne(v0) | ((u32)bf16rne(v1) << 16),
                   (u32)bf16rne(v2) | ((u32)bf16rne(v3) << 16));
  }
}

// ---------------------------------------------------------------------------
// tail, 8 WAVES (512 thr): Wo GEMM 8-wave TM=128 (blocks 0..255, clone of
// mfma_gemm_qkv structure, fp32 epilogue) + attn_mean 8-wave (blocks
// 256..767, r20-validated port). 16 KB shared pool aliased by branch.
// ---------------------------------------------------------------------------
__global__ __launch_bounds__(512) void tail(
    const u16* __restrict__ xhi, const u16* __restrict__ WoThi,
    const float* __restrict__ bo, float* __restrict__ out,
    const u16* __restrict__ QK, const float* __restrict__ mrow,
    const float* __restrict__ linv, float* __restrict__ am_out) {
  __shared__ u16 pool[2 * 128 * 32];  // 16 KB
  const int tid = threadIdx.x;
  const int lane = tid & 63, wv = tid >> 6;     // 8 waves
  const int l15 = lane & 15, g = lane >> 4;

  if (blockIdx.x < 256) {
    // ---- Wo GEMM: 128x128 tile, 8 waves 4x2 (each 32x64), BK=32 ----
    u16(*Ah)[32] = (u16(*)[32])pool;              // [128][32]
    u16(*Bh)[32] = (u16(*)[32])(pool + 128 * 32); // [128][32]
    const int wr = wv >> 1, wc = wv & 1;
    const int swz = ((int)blockIdx.x & 7) * 32 + ((int)blockIdx.x >> 3);
    const int m0 = (swz % 32) * 128, n0 = (swz / 32) * 128;
    const int Kd = 1024;
    f32x4 acc[2][4];
#pragma unroll
    for (int i = 0; i < 2; i++)
#pragma unroll
      for (int j = 0; j < 4; j++) {
        acc[i][j][0] = 0.f; acc[i][j][1] = 0.f;
        acc[i][j][2] = 0.f; acc[i][j][3] = 0.f;
      }
    const int fo = 8 * g;
    const int fr = l15;
    const int srow = lane >> 2;
    const int scol = (lane & 3) * 8;
#pragma unroll 1
    for (int k0 = 0; k0 < Kd; k0 += 32) {
      {  // wave wv stages A-chunk wv and B-chunk wv (16 rows each)
        size_t ga = (size_t)(m0 + wv * 16 + srow) * Kd + k0 + scol;
        gload_lds16(&xhi[ga], ((u16*)Ah) + wv * 512);
        size_t gb = (size_t)(n0 + wv * 16 + srow) * Kd + k0 + scol;
        gload_lds16(&WoThi[gb], ((u16*)Bh) + wv * 512);
      }
      __syncthreads();
      bf16x8 bhf[4];
#pragma unroll
      for (int nf = 0; nf < 4; nf++) {
        int r = wc * 64 + nf * 16 + fr;
        bhf[nf] = *(bf16x8*)&Bh[r][fo];
      }
#pragma unroll
      for (int mf = 0; mf < 2; mf++) {
        int r = wr * 32 + mf * 16 + fr;
        bf16x8 ahf = *(bf16x8*)&Ah[r][fo];
#pragma unroll
        for (int nf = 0; nf < 4; nf++)
          acc[mf][nf] = __builtin_amdgcn_mfma_f32_16x16x32_bf16(bhf[nf], ahf, acc[mf][nf], 0, 0, 0);
      }
      __syncthreads();
    }
    const int rq = g;
#pragma unroll
    for (int mf = 0; mf < 2; mf++) {
      int m = m0 + wr * 32 + mf * 16 + fr;
#pragma unroll
      for (int nf = 0; nf < 4; nf++) {
        int nb = n0 + wc * 64 + nf * 16 + rq * 4;
        float4 b4 = *(const float4*)&bo[nb];
        float4 o;
        o.x = acc[mf][nf][0] + b4.x;
        o.y = acc[mf][nf][1] + b4.y;
        o.z = acc[mf][nf][2] + b4.z;
        o.w = acc[mf][nf][3] + b4.w;
        *(float4*)&out[(size_t)m * 1024 + nb] = o;
      }
    }
  } else {
    // ---- attn_mean: 8 waves, 128 q rows x 64 k cols, 16-head loop ----
    u16(*Kh_s)[LSTR] = (u16(*)[LSTR])pool;  // [64][72] = 9.2 KB < 16 KB
    const int bi0 = (int)blockIdx.x - 256;
    const int bi = (bi0 & 7) * 64 + (bi0 >> 3);   // XCD swizzle (512 = 8*64)
    const int kc = bi & 15, qt = (bi >> 4) & 7, b = bi >> 7;
    const int q0 = qt * 128 + wv * 16, k0 = kc * 64;
    const int sr = tid >> 3, scs = (tid & 7) * 8; // staging: 1 uint4/thread
    float am[4][4] = {};
    uint4 kreg;
    bf16x8 qhc0, qhc1, qhn0, qhn1;
#define LOAD_K(h_)                                                            \
    kreg = *(const uint4*)&QK[(size_t)(b * T_ + k0 + sr) * 2048 + 1024 + (h_) * DH_ + scs];
#define LOAD_Q(h_, d0, d1)                                                    \
    {                                                                         \
      size_t qoff = (size_t)(b * T_ + q0 + l15) * 2048 + (h_) * DH_;          \
      d0 = *(const bf16x8*)&QK[qoff + 8 * g];                                 \
      d1 = *(const bf16x8*)&QK[qoff + 32 + 8 * g];                            \
    }
    LOAD_K(0);
    LOAD_Q(0, qhc0, qhc1);
#pragma unroll 1
    for (int h = 0; h < H_; h++) {
      *(uint4*)&Kh_s[sr][scs] = kreg;
      __syncthreads();
      if (h < 15) { LOAD_K(h + 1); LOAD_Q(h + 1, qhn0, qhn1); }
      f32x4 accs[4];
#pragma unroll
      for (int mf = 0; mf < 4; mf++) {
        accs[mf][0] = 0.f; accs[mf][1] = 0.f; accs[mf][2] = 0.f; accs[mf][3] = 0.f;
      }
#pragma unroll
      for (int mf = 0; mf < 4; mf++) {
        bf16x8 kh0 = *(bf16x8*)&Kh_s[mf * 16 + l15][8 * g];
        bf16x8 kh1 = *(bf16x8*)&Kh_s[mf * 16 + l15][32 + 8 * g];
        accs[mf] = __builtin_amdgcn_mfma_f32_16x16x32_bf16(kh0, qhc0, accs[mf], 0, 0, 0);
        accs[mf] = __builtin_amdgcn_mfma_f32_16x16x32_bf16(kh1, qhc1, accs[mf], 0, 0, 0);
      }
      const float mq = mrow[(b * H_ + h) * T_ + q0 + l15];
      const float li = linv[(b * H_ + h) * T_ + q0 + l15];
#pragma unroll
      for (int mf = 0; mf < 4; mf++)
#pragma unroll
        for (int r = 0; r < 4; r++)
          am[mf][r] += __builtin_amdgcn_exp2f(accs[mf][r] - mq) * li;
      __syncthreads();
      qhc0 = qhn0; qhc1 = qhn1;
    }
#undef LOAD_K
#undef LOAD_Q
    const float inv16 = 1.0f / 16.0f;
#pragma unroll
    for (int mf = 0; mf < 4; mf++) {
      float4 o;
      o.x = am[mf][0] * inv16; o.y = am[mf][1] * inv16;
      o.z = am[mf][2] * inv16; o.w = am[mf][3] * inv16;
      *(float4*)&am_out[(size_t)(b * T_ + q0 + l15) * T_ + k0 + 16 * mf + 4 * g] = o;
    }
  }
}

// ---------------------------------------------------------------------------
extern "C" void kernel_launch(void* const* d_in, const int* in_sizes, int n_in,
                              void* d_out, int out_size, void* d_ws, size_t ws_size,
                              hipStream_t stream) {
  const float* x  = (const float*)d_in[0];
  const float* Wq = (const float*)d_in[1];
  const float* bq = (const float*)d_in[2];
  const float* Wk = (const float*)d_in[3];
  const float* bk = (const float*)d_in[4];
  const float* Wv = (const float*)d_in[5];
  const float* bv = (const float*)d_in[6];
  const float* Wo = (const float*)d_in[7];
  const float* bo = (const float*)d_in[8];

  float* out = (float*)d_out;                      // [B,T,D]
  float* am  = out + (size_t)B_ * T_ * D_;         // [B,T,T]

  char* w = (char*)d_ws;
  u16* QK    = (u16*)w; w += (size_t)4096 * 2048 * 2;  // Q (pre-scaled) | K
  u16* Vt    = (u16*)w; w += (size_t)64 * 4096 * 2;
  u16* xhi   = (u16*)w; w += (size_t)4096 * 1024 * 2;  // x-hi, then out_pre hi
  u16* WcThi = (u16*)w; w += (size_t)NCAT * 1024 * 2;
  u16* WoThi = (u16*)w; w += (size_t)1024 * 1024 * 2;
  float* mrow  = (float*)w; w += (size_t)B_ * H_ * T_ * 4;
  float* linvp = (float*)w; w += (size_t)B_ * H_ * T_ * 4;
  float* bcat  = (float*)w; w += (size_t)NCAT * 4;

  prep<<<2833, 256, 0, stream>>>(x, Wq, Wk, Wv, Wo, bq, bk, bv,
                                 xhi, WcThi, WoThi, bcat);

  // QKV GEMM (1-pass, BK=32, 8-wave, 2-barrier, XCD-swizzled) -> QK, Vt
  mfma_gemm_qkv<<<544, 512, 0, stream>>>(xhi, WcThi, bcat, QK, Vt);

  attn_fused_mfma<<<512, 512, 0, stream>>>(QK, Vt, mrow, linvp, xhi);

  // tail: Wo GEMM (8-wave TM=128) + attn_mean (8-wave) in one launch
  tail<<<768, 512, 0, stream>>>(xhi, WoThi, bo, out, QK, mrow, linvp, am);
}